// Round 11
// baseline (737.258 us; speedup 1.0000x reference)
//
#include <hip/hip_runtime.h>
#include <math.h>

#define HEADS1 4
#define HID 64
#define LSTM_H 32
#define IN_F 128
#define T_STEPS 50
#define NEG_SLOPE 0.2f
#define EPS_A 1e-16f

typedef __attribute__((ext_vector_type(8))) short short8;
typedef __attribute__((ext_vector_type(4))) float floatx4;
typedef __attribute__((ext_vector_type(4))) unsigned uint32x4;

// ---------- helpers ----------
// Single-instruction reciprocal (1 ulp). Without -ffast-math the compiler
// expands 1.0f/x to the ~12-inst IEEE div sequence. [r16: -42% on lstm]
__device__ __forceinline__ float frcp(float x) {
    float r;
    asm("v_rcp_f32 %0, %1" : "=v"(r) : "v"(x));
    return r;
}
__device__ __forceinline__ float sigf(float x) { return frcp(1.0f + __expf(-x)); }
__device__ __forceinline__ float tanhfast(float x) {
    float e = __expf(2.0f * x);
    return 1.0f - 2.0f * frcp(e + 1.0f);
}
__device__ __forceinline__ unsigned short f2bf(float f) {
    unsigned u = __float_as_uint(f);
    unsigned r = (u + 0x7FFFu + ((u >> 16) & 1u)) >> 16;
    return (unsigned short)r;
}
__device__ __forceinline__ float bf2f(unsigned short s) {
    return __uint_as_float(((unsigned)s) << 16);
}
// HW packed fp32->bf16 (2 values / instruction); no builtin on gfx950, inline asm.
__device__ __forceinline__ unsigned cvt_pk_bf16(float a, float b) {
    unsigned r;
    asm("v_cvt_pk_bf16_f32 %0, %1, %2" : "=v"(r) : "v"(a), "v"(b));
    return r;
}
__device__ __forceinline__ float lo16f(unsigned p) { return __uint_as_float(p << 16); }
__device__ __forceinline__ float hi16f(unsigned p) { return __uint_as_float(p & 0xffff0000u); }
__device__ __forceinline__ short8 bc8(uint32x4 v) { return __builtin_bit_cast(short8, v); }

// ---------- weight transpose+split prepack for MFMA GEMM ----------
template <int KK>
__global__ void prep_wt(const float* __restrict__ W, unsigned short* __restrict__ th,
                        unsigned short* __restrict__ tl, int total, int NC) {
    int i = blockIdx.x * 256 + threadIdx.x;
    if (i >= total) return;
    int n = i / KK, k = i - n * KK;
    float v = W[k * NC + n];
    unsigned short h = f2bf(v);
    th[i] = h;
    tl[i] = f2bf(v - bf2f(h));
}

// ---------- MFMA GEMM: C[M,NC] = A[M,K] @ B[K,NC], split-bf16 3-product ----
template <int K, int NC>
__global__ __launch_bounds__(256)
void gemm_mfma(const float* __restrict__ A, const unsigned short* __restrict__ Bth,
               const unsigned short* __restrict__ Btl, float* __restrict__ C, int M) {
    __shared__ float sA[128][44];            // 22.5 KB
    __shared__ unsigned short sBh[64][40];   // 5 KB
    __shared__ unsigned short sBl[64][40];   // 5 KB
    const int tid = threadIdx.x;
    const int wave = tid >> 6, lane = tid & 63;
    const int wr = wave >> 1, wc = wave & 1;
    const int row0 = blockIdx.x * 128;
    const int col0 = blockIdx.y * 64;
    const int l15 = lane & 15, l4 = lane >> 4;

    floatx4 acc[4][2];
#pragma unroll
    for (int rb = 0; rb < 4; rb++)
#pragma unroll
        for (int cb = 0; cb < 2; cb++) acc[rb][cb] = (floatx4){0.f, 0.f, 0.f, 0.f};

    for (int k0 = 0; k0 < K; k0 += 32) {
        __syncthreads();
#pragma unroll
        for (int q = 0; q < 4; q++) {
            int idx = q * 256 + tid;
            int row = idx >> 3, seg = idx & 7;
            int gr = row0 + row;
            float4 v = (gr < M) ? *(const float4*)&A[(size_t)gr * K + k0 + seg * 4]
                                : make_float4(0.f, 0.f, 0.f, 0.f);
            *(float4*)&sA[row][seg * 4] = v;
        }
        {
            int col = tid >> 2, seg = tid & 3;
            size_t gb = (size_t)(col0 + col) * K + k0 + seg * 8;
            *(short8*)&sBh[col][seg * 8] = *(const short8*)&Bth[gb];
            *(short8*)&sBl[col][seg * 8] = *(const short8*)&Btl[gb];
        }
        __syncthreads();

        short8 bh0 = *(const short8*)&sBh[wc * 32 + 0 + l15][l4 * 8];
        short8 bl0 = *(const short8*)&sBl[wc * 32 + 0 + l15][l4 * 8];
        short8 bh1 = *(const short8*)&sBh[wc * 32 + 16 + l15][l4 * 8];
        short8 bl1 = *(const short8*)&sBl[wc * 32 + 16 + l15][l4 * 8];

#pragma unroll
        for (int rb = 0; rb < 4; rb++) {
            int row = wr * 64 + rb * 16 + l15;
            floatx4 a0 = *(const floatx4*)&sA[row][l4 * 8 + 0];
            floatx4 a1 = *(const floatx4*)&sA[row][l4 * 8 + 4];
            unsigned p0 = cvt_pk_bf16(a0[0], a0[1]);
            unsigned p1 = cvt_pk_bf16(a0[2], a0[3]);
            unsigned p2 = cvt_pk_bf16(a1[0], a1[1]);
            unsigned p3 = cvt_pk_bf16(a1[2], a1[3]);
            uint32x4 hp = {p0, p1, p2, p3};
            short8 Ah = bc8(hp);
            unsigned q0 = cvt_pk_bf16(a0[0] - lo16f(p0), a0[1] - hi16f(p0));
            unsigned q1 = cvt_pk_bf16(a0[2] - lo16f(p1), a0[3] - hi16f(p1));
            unsigned q2 = cvt_pk_bf16(a1[0] - lo16f(p2), a1[1] - hi16f(p2));
            unsigned q3 = cvt_pk_bf16(a1[2] - lo16f(p3), a1[3] - hi16f(p3));
            uint32x4 lp = {q0, q1, q2, q3};
            short8 Al = bc8(lp);

            acc[rb][0] = __builtin_amdgcn_mfma_f32_16x16x32_bf16(Ah, bh0, acc[rb][0], 0, 0, 0);
            acc[rb][0] = __builtin_amdgcn_mfma_f32_16x16x32_bf16(Ah, bl0, acc[rb][0], 0, 0, 0);
            acc[rb][0] = __builtin_amdgcn_mfma_f32_16x16x32_bf16(Al, bh0, acc[rb][0], 0, 0, 0);
            acc[rb][1] = __builtin_amdgcn_mfma_f32_16x16x32_bf16(Ah, bh1, acc[rb][1], 0, 0, 0);
            acc[rb][1] = __builtin_amdgcn_mfma_f32_16x16x32_bf16(Ah, bl1, acc[rb][1], 0, 0, 0);
            acc[rb][1] = __builtin_amdgcn_mfma_f32_16x16x32_bf16(Al, bh1, acc[rb][1], 0, 0, 0);
        }
    }

#pragma unroll
    for (int rb = 0; rb < 4; rb++)
#pragma unroll
        for (int cb = 0; cb < 2; cb++)
#pragma unroll
            for (int q = 0; q < 4; q++) {
                int row = row0 + wr * 64 + rb * 16 + l4 * 4 + q;
                int col = col0 + wc * 32 + cb * 16 + l15;
                if (row < M) C[(size_t)row * NC + col] = acc[rb][cb][q];
            }
}

// ---------- attention scores ----------
__global__ void att_scores(const float* __restrict__ h, const float* __restrict__ att_s,
                           const float* __restrict__ att_d, float* __restrict__ as_,
                           float* __restrict__ ad_, int NH, int Hmask) {
    int i = blockIdx.x * blockDim.x + threadIdx.x;
    if (i >= NH) return;
    int hh = i & Hmask;
    const float* row = h + (size_t)i * HID;
    float s = 0.0f, d = 0.0f;
#pragma unroll 8
    for (int c = 0; c < HID; c++) {
        float v = row[c];
        s += v * att_s[hh * HID + c];
        d += v * att_d[hh * HID + c];
    }
    as_[i] = s;
    ad_[i] = d;
}

// ---------- CSR build ----------
__global__ void count_deg(const int* __restrict__ dsts, int E, int ET, int* __restrict__ cnt) {
    int e = blockIdx.x * blockDim.x + threadIdx.x;
    if (e >= ET) return;
    int d = (e < E) ? dsts[e] : (e - E);
    atomicAdd(&cnt[d], 1);
}

__global__ void scan1(const int* __restrict__ cnt, int* __restrict__ rowp,
                      int* __restrict__ bsum, int N) {
    __shared__ int tmp[256];
    int i = blockIdx.x * 256 + threadIdx.x;
    int v = (i < N) ? cnt[i] : 0;
    tmp[threadIdx.x] = v;
    __syncthreads();
    for (int off = 1; off < 256; off <<= 1) {
        int t = (threadIdx.x >= (unsigned)off) ? tmp[threadIdx.x - off] : 0;
        __syncthreads();
        tmp[threadIdx.x] += t;
        __syncthreads();
    }
    if (i < N) rowp[i] = tmp[threadIdx.x] - v;
    if (threadIdx.x == 255) bsum[blockIdx.x] = tmp[255];
}

__global__ void scan2(int* __restrict__ bsum, int nb) {
    __shared__ int tmp[256];
    int v = (threadIdx.x < (unsigned)nb) ? bsum[threadIdx.x] : 0;
    tmp[threadIdx.x] = v;
    __syncthreads();
    for (int off = 1; off < 256; off <<= 1) {
        int t = (threadIdx.x >= (unsigned)off) ? tmp[threadIdx.x - off] : 0;
        __syncthreads();
        tmp[threadIdx.x] += t;
        __syncthreads();
    }
    if (threadIdx.x < (unsigned)nb) bsum[threadIdx.x] = tmp[threadIdx.x] - v;
}

__global__ void scan3(int* __restrict__ rowp, const int* __restrict__ bsum, int N, int ET) {
    int i = blockIdx.x * 256 + threadIdx.x;
    if (i < N) rowp[i] += bsum[blockIdx.x];
    if (i == 0) rowp[N] = ET;
}

__global__ void scatter_edges(const int* __restrict__ dsts, int E, int ET,
                              const int* __restrict__ rowp, int* __restrict__ cursor,
                              int* __restrict__ eid) {
    int e = blockIdx.x * blockDim.x + threadIdx.x;
    if (e >= ET) return;
    int d = (e < E) ? dsts[e] : (e - E);
    int pos = atomicAdd(&cursor[d], 1);
    eid[rowp[d] + pos] = e;
}

// ---------- GAT layer-1 aggregation: single pass, one wave per dst, 4 heads ----------
__global__ __launch_bounds__(256)
void gat_agg4_sp(const int* __restrict__ srcs, int E,
                 const int* __restrict__ rowp, const int* __restrict__ eid,
                 const float* __restrict__ as_, const float* __restrict__ ad_,
                 const float* __restrict__ hfeat, const float* __restrict__ bias,
                 float* __restrict__ g, int N) {
    __shared__ float s_alpha[4][64][4];
    const int wave = threadIdx.x >> 6;
    const int lane = threadIdx.x & 63;
    const int head = lane >> 4;
    const int dst = blockIdx.x * 4 + wave;
    if (dst >= N) return;
    const int start = rowp[dst], end = rowp[dst + 1];
    const float4 adv = ((const float4*)ad_)[dst];
    const float4* h4 = (const float4*)hfeat;

    float4 dsum = make_float4(0.f, 0.f, 0.f, 0.f);
    float4 acc  = make_float4(0.f, 0.f, 0.f, 0.f);

    for (int i0 = start; i0 < end; i0 += 64) {
        int cnt = min(64, end - i0);
        int i = i0 + lane;
        int s = 0;
        if (i < end) {
            int e = eid[i];
            s = (e < E) ? srcs[e] : (e - E);
            float4 a = ((const float4*)as_)[s];
            float tx, ex;
            tx = a.x + adv.x; tx = (tx > 0.f) ? tx : NEG_SLOPE * tx; ex = __expf(tx);
            dsum.x += ex; s_alpha[wave][lane][0] = ex;
            tx = a.y + adv.y; tx = (tx > 0.f) ? tx : NEG_SLOPE * tx; ex = __expf(tx);
            dsum.y += ex; s_alpha[wave][lane][1] = ex;
            tx = a.z + adv.z; tx = (tx > 0.f) ? tx : NEG_SLOPE * tx; ex = __expf(tx);
            dsum.z += ex; s_alpha[wave][lane][2] = ex;
            tx = a.w + adv.w; tx = (tx > 0.f) ? tx : NEG_SLOPE * tx; ex = __expf(tx);
            dsum.w += ex; s_alpha[wave][lane][3] = ex;
        }
        __builtin_amdgcn_wave_barrier();
#pragma unroll 4
        for (int k = 0; k < cnt; k++) {
            float a_k = s_alpha[wave][k][head];   // 16-lane broadcast read
            int   s_k = __shfl(s, k);
            float4 hv = h4[(size_t)s_k * 64 + lane];
            acc.x += a_k * hv.x; acc.y += a_k * hv.y;
            acc.z += a_k * hv.z; acc.w += a_k * hv.w;
        }
        __builtin_amdgcn_wave_barrier();
    }
#pragma unroll
    for (int mk = 32; mk >= 1; mk >>= 1) {
        dsum.x += __shfl_xor(dsum.x, mk);
        dsum.y += __shfl_xor(dsum.y, mk);
        dsum.z += __shfl_xor(dsum.z, mk);
        dsum.w += __shfl_xor(dsum.w, mk);
    }
    float den = (head == 0) ? dsum.x : (head == 1) ? dsum.y : (head == 2) ? dsum.z : dsum.w;
    float inv = 1.0f / (den + EPS_A);
    float4 b4 = ((const float4*)bias)[lane];
    float4 r;
    r.x = acc.x * inv + b4.x; r.x = (r.x > 0.f) ? r.x : __expf(r.x) - 1.f;
    r.y = acc.y * inv + b4.y; r.y = (r.y > 0.f) ? r.y : __expf(r.y) - 1.f;
    r.z = acc.z * inv + b4.z; r.z = (r.z > 0.f) ? r.z : __expf(r.z) - 1.f;
    r.w = acc.w * inv + b4.w; r.w = (r.w > 0.f) ? r.w : __expf(r.w) - 1.f;
    ((float4*)g)[(size_t)dst * 64 + lane] = r;
}

// ---------- GAT layer-2 aggregation: single pass, one wave per dst, H=1 ----------
__global__ __launch_bounds__(256)
void gat_agg1_sp(const int* __restrict__ srcs, int E,
                 const int* __restrict__ rowp, const int* __restrict__ eid,
                 const float* __restrict__ as_, const float* __restrict__ ad_,
                 const float* __restrict__ hfeat, const float* __restrict__ bias,
                 float* __restrict__ g, int N) {
    __shared__ float s_alpha[4][64];
    const int wave = threadIdx.x >> 6;
    const int lane = threadIdx.x & 63;
    const int dst = blockIdx.x * 4 + wave;
    if (dst >= N) return;
    const int start = rowp[dst], end = rowp[dst + 1];
    const float adv = ad_[dst];

    float dsum = 0.0f, acc = 0.0f;
    for (int i0 = start; i0 < end; i0 += 64) {
        int cnt = min(64, end - i0);
        int i = i0 + lane;
        int s = 0;
        if (i < end) {
            int e = eid[i];
            s = (e < E) ? srcs[e] : (e - E);
            float t = as_[s] + adv;
            t = (t > 0.f) ? t : NEG_SLOPE * t;
            float ex = __expf(t);
            dsum += ex;
            s_alpha[wave][lane] = ex;
        }
        __builtin_amdgcn_wave_barrier();
#pragma unroll 4
        for (int k = 0; k < cnt; k++) {
            float a_k = s_alpha[wave][k];         // full-wave broadcast read
            int   s_k = __shfl(s, k);
            acc += a_k * hfeat[(size_t)s_k * 64 + lane];
        }
        __builtin_amdgcn_wave_barrier();
    }
#pragma unroll
    for (int mk = 32; mk >= 1; mk >>= 1) dsum += __shfl_xor(dsum, mk);
    g[(size_t)dst * 64 + lane] = acc / (dsum + EPS_A) + bias[lane];
}

// ---------- LSTM weight prepack (runs once, 1 block) ----------
// Layout [kk][which][hf][lane]: fragment for gate kk (i,f,g,o), type which
// (B2/BH/BL), unit-half hf. Serves both the pair-split and wave-private
// kernels (block b = kk*2+hf).
__global__ void prep_wsplit(const float* __restrict__ Wih, const float* __restrict__ Whh,
                            const float* __restrict__ bih, const float* __restrict__ bhh,
                            uint32x4* __restrict__ wsp) {
    const int tid = threadIdx.x;          // 0..511
    const int kk = tid >> 7, sub = (tid >> 6) & 1, lane = tid & 63;
    const int grp = lane >> 4, col = lane & 15;
    const int krow = grp * 8;
    const int n = (sub + kk * 2) * 16 + col;
    float w[8];
    *(float4*)&w[0] = *(const float4*)&Whh[n * 32 + krow + 0];
    *(float4*)&w[4] = *(const float4*)&Whh[n * 32 + krow + 4];
    unsigned hi[8], lo[8];
#pragma unroll
    for (int j = 0; j < 8; j++) {
        unsigned short hs = f2bf(w[j]);
        hi[j] = hs;
        lo[j] = f2bf(w[j] - bf2f(hs));
    }
    uint32x4 BH = {hi[0] | (hi[1] << 16), hi[2] | (hi[3] << 16),
                   hi[4] | (hi[5] << 16), hi[6] | (hi[7] << 16)};
    uint32x4 BL = {lo[0] | (lo[1] << 16), lo[2] | (lo[3] << 16),
                   lo[4] | (lo[5] << 16), lo[6] | (lo[7] << 16)};
    float wi0 = Wih[n * 3 + 0], wi1 = Wih[n * 3 + 1], wi2 = Wih[n * 3 + 2];
    float bb = bih[n] + bhh[n];
    unsigned h0 = f2bf(wi0), h1 = f2bf(wi1), h2 = f2bf(wi2), hb = f2bf(bb);
    uint32x4 B2 = {0u, 0u, 0u, 0u};
    if (grp == 0) {
        unsigned bl_ = f2bf(bb - bf2f((unsigned short)hb));
        B2[0] = h0 | (h1 << 16); B2[1] = h2 | (hb << 16);
        B2[2] = h0 | (h1 << 16); B2[3] = h2 | (bl_ << 16);
    } else if (grp == 1) {
        unsigned l0 = f2bf(wi0 - bf2f((unsigned short)h0));
        unsigned l1 = f2bf(wi1 - bf2f((unsigned short)h1));
        unsigned l2 = f2bf(wi2 - bf2f((unsigned short)h2));
        B2[0] = l0 | (l1 << 16); B2[1] = l2;
    }
    wsp[((kk * 3 + 0) * 2 + sub) * 64 + lane] = B2;
    wsp[((kk * 3 + 1) * 2 + sub) * 64 + lane] = BH;
    wsp[((kk * 3 + 2) * 2 + sub) * 64 + lane] = BL;
}

// ---------- LSTM via MFMA (split-bf16), round-19: wave-private recurrence ----
// Delta vs round 18: NO __syncthreads in the t-loop. r18 post-mortem: grid is
// only 3.05 blocks/CU (782 blocks) so the LDS cut raised the residency CAP but
// not residency; dur barely moved. The 2.3x gap between measured 445K cycles
// and the ~81us issue floor is the per-ts block barrier coupling 8 waves (4
// INDEPENDENT pairs) to the slowest chain, 50 times. Fix: one wave owns 16
// nodes end-to-end (all 8 gate-blocks, 32 MFMA/ts, 24 prepacked fragments);
// h exchange is wave-internal via a wave-private LDS buffer + wave_barrier
// (a free scheduling fence). Block 256 thr = 4 fully independent waves.
// VERIFY: Workgroup_Size 256, LDS 9216, dur ~95-135us, MfmaUtil ~30%.
__global__ __launch_bounds__(256)
void lstm_mfma(const float* __restrict__ seq, const uint32x4* __restrict__ wsp,
               float* __restrict__ t_out, int N) {
    __shared__ float s_h[4][16][36];        // per-wave [node][unit+pad], 9.2 KB

    const int tid  = threadIdx.x;
    const int wave = tid >> 6, lane = tid & 63;
    const int grp  = lane >> 4, col = lane & 15;
    const int node0 = blockIdx.x * 64 + wave * 16;

    // ---- 24 weight fragments: coalesced 16B loads, no arithmetic ----
#define LF(KK, W, HF) wsp[(((KK) * 3 + (W)) * 2 + (HF)) * 64 + lane]
    uint32x4 B2_i0 = LF(0, 0, 0), BH_i0 = LF(0, 1, 0), BL_i0 = LF(0, 2, 0);
    uint32x4 B2_i1 = LF(0, 0, 1), BH_i1 = LF(0, 1, 1), BL_i1 = LF(0, 2, 1);
    uint32x4 B2_f0 = LF(1, 0, 0), BH_f0 = LF(1, 1, 0), BL_f0 = LF(1, 2, 0);
    uint32x4 B2_f1 = LF(1, 0, 1), BH_f1 = LF(1, 1, 1), BL_f1 = LF(1, 2, 1);
    uint32x4 B2_g0 = LF(2, 0, 0), BH_g0 = LF(2, 1, 0), BL_g0 = LF(2, 2, 0);
    uint32x4 B2_g1 = LF(2, 0, 1), BH_g1 = LF(2, 1, 1), BL_g1 = LF(2, 2, 1);
    uint32x4 B2_o0 = LF(3, 0, 0), BH_o0 = LF(3, 1, 0), BL_o0 = LF(3, 2, 0);
    uint32x4 B2_o1 = LF(3, 0, 1), BH_o1 = LF(3, 1, 1), BL_o1 = LF(3, 2, 1);
#undef LF

    // ---- zero this wave's h buffer (wave-private; no block sync needed) ----
    for (int i = lane; i < 16 * 36; i += 64) (&s_h[wave][0][0])[i] = 0.0f;
    __builtin_amdgcn_wave_barrier();

    float cA0 = 0.f, cA1 = 0.f, cA2 = 0.f, cA3 = 0.f;   // units hf=0
    float cB0 = 0.f, cB1 = 0.f, cB2 = 0.f, cB3 = 0.f;   // units hf=1
    float hA0 = 0.f, hA1 = 0.f, hA2 = 0.f, hA3 = 0.f;
    float hB0 = 0.f, hB1 = 0.f, hB2 = 0.f, hB3 = 0.f;
    const floatx4 zac = {0.f, 0.f, 0.f, 0.f};

    const int nodeX = node0 + col;
    const bool vx = (nodeX < N) && (grp < 2);
    const bool g0 = (grp == 0);
    const float* xp = seq + (size_t)nodeX * (T_STEPS * 3);

    float xv0 = vx ? xp[0] : 0.0f;
    float xv1 = vx ? xp[1] : 0.0f;
    float xv2 = vx ? xp[2] : 0.0f;

#pragma unroll 1
    for (int t = 0; t < T_STEPS; t++) {
        // ---- A2: x hi/lo + ones in K-slots (grp0: k'0-7, grp1: k'8-10) ----
        unsigned w0 = cvt_pk_bf16(xv0, xv1);
        unsigned w1 = cvt_pk_bf16(xv2, g0 ? 1.0f : 0.0f);
        float e0 = xv0 - lo16f(w0);
        float e1 = xv1 - hi16f(w0);
        float e2 = xv2 - lo16f(w1);
        unsigned w2 = g0 ? cvt_pk_bf16(e0, e1) : 0u;
        unsigned w3 = g0 ? cvt_pk_bf16(e2, 1.0f) : 0u;
        uint32x4 a2p = {w0, w1, w2, w3};
        short8 A2 = bc8(a2p);

        // ---- A (h) hi/lo from wave-private LDS ----
        const float* hr = &s_h[wave][col][grp * 8];
        floatx4 h0 = *(const floatx4*)&hr[0];
        floatx4 h1 = *(const floatx4*)&hr[4];
        unsigned p0 = cvt_pk_bf16(h0[0], h0[1]);
        unsigned p1 = cvt_pk_bf16(h0[2], h0[3]);
        unsigned p2 = cvt_pk_bf16(h1[0], h1[1]);
        unsigned p3 = cvt_pk_bf16(h1[2], h1[3]);
        uint32x4 hip = {p0, p1, p2, p3};
        short8 Ahi = bc8(hip);
        unsigned q0 = cvt_pk_bf16(h0[0] - lo16f(p0), h0[1] - hi16f(p0));
        unsigned q1 = cvt_pk_bf16(h0[2] - lo16f(p1), h0[3] - hi16f(p1));
        unsigned q2 = cvt_pk_bf16(h1[0] - lo16f(p2), h1[1] - hi16f(p2));
        unsigned q3 = cvt_pk_bf16(h1[2] - lo16f(p3), h1[3] - hi16f(p3));
        uint32x4 lop = {q0, q1, q2, q3};
        short8 Alo = bc8(lop);

        // ---- prefetch next x (clamped offset; hidden under MFMAs+gates) ----
        {
            int tn = (t + 1 < T_STEPS) ? (t + 1) : t;
            xv0 = vx ? xp[tn * 3 + 0] : 0.0f;
            xv1 = vx ? xp[tn * 3 + 1] : 0.0f;
            xv2 = vx ? xp[tn * 3 + 2] : 0.0f;
        }

        // ---- 8 gate-blocks x 4 MFMAs (all 32 units of this wave's 16 nodes) ----
#define GBLK(D, B2V, BHV, BLV)                                                   \
        floatx4 D = __builtin_amdgcn_mfma_f32_16x16x32_bf16(A2, bc8(B2V), zac, 0, 0, 0); \
        D = __builtin_amdgcn_mfma_f32_16x16x32_bf16(Alo, bc8(BHV), D, 0, 0, 0);  \
        D = __builtin_amdgcn_mfma_f32_16x16x32_bf16(Ahi, bc8(BLV), D, 0, 0, 0);  \
        D = __builtin_amdgcn_mfma_f32_16x16x32_bf16(Ahi, bc8(BHV), D, 0, 0, 0);
        GBLK(di0, B2_i0, BH_i0, BL_i0)
        GBLK(di1, B2_i1, BH_i1, BL_i1)
        GBLK(df0, B2_f0, BH_f0, BL_f0)
        GBLK(df1, B2_f1, BH_f1, BL_f1)
        GBLK(dg0, B2_g0, BH_g0, BL_g0)
        GBLK(dg1, B2_g1, BH_g1, BL_g1)
        GBLK(do0, B2_o0, BH_o0, BL_o0)
        GBLK(do1, B2_o1, BH_o1, BL_o1)
#undef GBLK

        // ---- gates; per-q unrolled, named state ----
        {
            float ig, fg, gv, og;
            ig = sigf(di0[0]); fg = sigf(df0[0]); gv = tanhfast(dg0[0]); og = sigf(do0[0]);
            cA0 = fg * cA0 + ig * gv; hA0 = og * tanhfast(cA0);
            ig = sigf(di0[1]); fg = sigf(df0[1]); gv = tanhfast(dg0[1]); og = sigf(do0[1]);
            cA1 = fg * cA1 + ig * gv; hA1 = og * tanhfast(cA1);
            ig = sigf(di0[2]); fg = sigf(df0[2]); gv = tanhfast(dg0[2]); og = sigf(do0[2]);
            cA2 = fg * cA2 + ig * gv; hA2 = og * tanhfast(cA2);
            ig = sigf(di0[3]); fg = sigf(df0[3]); gv = tanhfast(dg0[3]); og = sigf(do0[3]);
            cA3 = fg * cA3 + ig * gv; hA3 = og * tanhfast(cA3);
            ig = sigf(di1[0]); fg = sigf(df1[0]); gv = tanhfast(dg1[0]); og = sigf(do1[0]);
            cB0 = fg * cB0 + ig * gv; hB0 = og * tanhfast(cB0);
            ig = sigf(di1[1]); fg = sigf(df1[1]); gv = tanhfast(dg1[1]); og = sigf(do1[1]);
            cB1 = fg * cB1 + ig * gv; hB1 = og * tanhfast(cB1);
            ig = sigf(di1[2]); fg = sigf(df1[2]); gv = tanhfast(dg1[2]); og = sigf(do1[2]);
            cB2 = fg * cB2 + ig * gv; hB2 = og * tanhfast(cB2);
            ig = sigf(di1[3]); fg = sigf(df1[3]); gv = tanhfast(dg1[3]); og = sigf(do1[3]);
            cB3 = fg * cB3 + ig * gv; hB3 = og * tanhfast(cB3);
        }

        // ---- h writeback (wave-private; D row = node 4*grp+q, col = unit) ----
        __builtin_amdgcn_wave_barrier();
        {
            float* hw = &s_h[wave][4 * grp][0];
            hw[0 * 36 + col]      = hA0;
            hw[1 * 36 + col]      = hA1;
            hw[2 * 36 + col]      = hA2;
            hw[3 * 36 + col]      = hA3;
            hw[0 * 36 + 16 + col] = hB0;
            hw[1 * 36 + 16 + col] = hB1;
            hw[2 * 36 + 16 + col] = hB2;
            hw[3 * 36 + 16 + col] = hB3;
        }
        __builtin_amdgcn_wave_barrier();
    }

    {
        int node = node0 + 4 * grp;
        if (node + 0 < N) { t_out[(size_t)(node + 0) * LSTM_H + col] = hA0;
                            t_out[(size_t)(node + 0) * LSTM_H + 16 + col] = hB0; }
        if (node + 1 < N) { t_out[(size_t)(node + 1) * LSTM_H + col] = hA1;
                            t_out[(size_t)(node + 1) * LSTM_H + 16 + col] = hB1; }
        if (node + 2 < N) { t_out[(size_t)(node + 2) * LSTM_H + col] = hA2;
                            t_out[(size_t)(node + 2) * LSTM_H + 16 + col] = hB2; }
        if (node + 3 < N) { t_out[(size_t)(node + 3) * LSTM_H + col] = hA3;
                            t_out[(size_t)(node + 3) * LSTM_H + 16 + col] = hB3; }
    }
}

// ---------- fusion MLP ----------
__global__ void fusion_kernel(const float* __restrict__ g2, const float* __restrict__ tt,
                              const float* __restrict__ Wf1, const float* __restrict__ bf1,
                              const float* __restrict__ Wf2, const float* __restrict__ bf2,
                              float* __restrict__ out, int N) {
    __shared__ float sW[96 * 64];
    __shared__ float sb1[64];
    __shared__ float sW2[128];
    for (int i = threadIdx.x; i < 96 * 64; i += 256) sW[i] = Wf1[i];
    if (threadIdx.x < 64) sb1[threadIdx.x] = bf1[threadIdx.x];
    if (threadIdx.x < 128) sW2[threadIdx.x] = Wf2[threadIdx.x];
    __syncthreads();
    const int wave = threadIdx.x >> 6;
    const int lane = threadIdx.x & 63;
    for (int n = blockIdx.x * 4 + wave; n < N; n += gridDim.x * 4) {
        const float* gn = g2 + (size_t)n * 64;
        const float* tn = tt + (size_t)n * 32;
        float acc = sb1[lane];
#pragma unroll 8
        for (int k = 0; k < 64; k++) acc += gn[k] * sW[k * 64 + lane];
#pragma unroll 8
        for (int k = 0; k < 32; k++) acc += tn[k] * sW[(64 + k) * 64 + lane];
        acc = fmaxf(acc, 0.0f);
        float o0 = acc * sW2[lane * 2 + 0];
        float o1 = acc * sW2[lane * 2 + 1];
#pragma unroll
        for (int mk = 32; mk >= 1; mk >>= 1) {
            o0 += __shfl_xor(o0, mk);
            o1 += __shfl_xor(o1, mk);
        }
        if (lane == 0) {
            out[(size_t)n * 2 + 0] = o0 + bf2[0];
            out[(size_t)n * 2 + 1] = o1 + bf2[1];
        }
    }
}

extern "C" void kernel_launch(void* const* d_in, const int* in_sizes, int n_in,
                              void* d_out, int out_size, void* d_ws, size_t ws_size,
                              hipStream_t stream) {
    const float* x      = (const float*)d_in[0];
    const int*   eidx   = (const int*)d_in[1];
    const float* seq    = (const float*)d_in[2];
    const float* W1     = (const float*)d_in[3];
    const float* att_s1 = (const float*)d_in[4];
    const float* att_d1 = (const float*)d_in[5];
    const float* bias1  = (const float*)d_in[6];
    const float* W2     = (const float*)d_in[7];
    const float* att_s2 = (const float*)d_in[8];
    const float* att_d2 = (const float*)d_in[9];
    const float* bias2  = (const float*)d_in[10];
    const float* Wih    = (const float*)d_in[11];
    const float* Whh    = (const float*)d_in[12];
    const float* bih    = (const float*)d_in[13];
    const float* bhh    = (const float*)d_in[14];
    const float* Wf1    = (const float*)d_in[15];
    const float* bf1    = (const float*)d_in[16];
    const float* Wf2    = (const float*)d_in[17];
    const float* bf2    = (const float*)d_in[18];
    float* out = (float*)d_out;

    const int N  = in_sizes[0] / IN_F;   // 50000
    const int E  = in_sizes[1] / 2;      // 800000
    const int ET = E + N;
    const int* srcs = eidx;
    const int* dsts = eidx + E;

    // workspace layout
    float* fws = (float*)d_ws;
    size_t o = 0;
    float* h1  = fws + o; o += (size_t)N * 256;
    float* g1  = fws + o; o += (size_t)N * 256;
    float* as1 = fws + o; o += (size_t)N * 4;
    float* ad1 = fws + o; o += (size_t)N * 4;
    int* cnt    = (int*)(fws + o);
    int* rowp   = cnt + N;
    int* cursor = rowp + N + 1;
    int* eid    = cursor + N;
    int* bsum   = eid + ET;
    // prepacked LSTM weight fragments (24.5 KB, 16B-aligned)
    uintptr_t wp_ = (uintptr_t)(bsum + 512);
    wp_ = (wp_ + 15) & ~(uintptr_t)15;
    uint32x4* wsp = (uint32x4*)wp_;
    // prepacked transposed GEMM weights (hi/lo): W1t 2x32768, W2t 2x16384 shorts
    unsigned short* w1h = (unsigned short*)(wsp + 1536);
    unsigned short* w1l = w1h + 32768;
    unsigned short* w2h = w1l + 32768;
    unsigned short* w2l = w2h + 16384;
    // layer-2 / LSTM aliases (h1 region dead after layer-1 aggregation)
    float* h2 = h1;                      // N*64
    float* g2 = h1 + (size_t)N * 64;     // N*64
    float* tt = h1 + (size_t)N * 128;    // N*32
    float* as2 = as1; float* ad2 = ad1;

    const int nTiles = (N + 255) / 256;
    dim3 blk(256);

    // ---- CSR build ----
    hipMemsetAsync(cnt, 0, (size_t)N * sizeof(int), stream);
    hipMemsetAsync(cursor, 0, (size_t)N * sizeof(int), stream);
    count_deg<<<(ET + 255) / 256, blk, 0, stream>>>(dsts, E, ET, cnt);
    scan1<<<nTiles, blk, 0, stream>>>(cnt, rowp, bsum, N);
    scan2<<<1, blk, 0, stream>>>(bsum, nTiles);
    scan3<<<(N + 256) / 256, blk, 0, stream>>>(rowp, bsum, N, ET);
    scatter_edges<<<(ET + 255) / 256, blk, 0, stream>>>(dsts, E, ET, rowp, cursor, eid);

    // ---- weight prepacks (tiny, once) ----
    prep_wsplit<<<1, 512, 0, stream>>>(Wih, Whh, bih, bhh, wsp);
    prep_wt<128><<<(32768 + 255) / 256, blk, 0, stream>>>(W1, w1h, w1l, 32768, 256);
    prep_wt<256><<<(16384 + 255) / 256, blk, 0, stream>>>(W2, w2h, w2l, 16384, 64);

    // ---- GAT layer 1 (MFMA split-bf16 GEMM) ----
    gemm_mfma<128, 256><<<dim3((N + 127) / 128, 4), blk, 0, stream>>>(x, w1h, w1l, h1, N);
    att_scores<<<(N * 4 + 255) / 256, blk, 0, stream>>>(h1, att_s1, att_d1, as1, ad1, N * 4, 3);
    gat_agg4_sp<<<(N + 3) / 4, blk, 0, stream>>>(srcs, E, rowp, eid, as1, ad1, h1, bias1, g1, N);

    // ---- LSTM (MFMA; wave-private recurrence, barrier-free t-loop) ----
    lstm_mfma<<<(N + 63) / 64, dim3(256), 0, stream>>>(seq, wsp, tt, N);

    // ---- GAT layer 2 (MFMA split-bf16 GEMM) ----
    gemm_mfma<256, 64><<<dim3((N + 127) / 128, 1), blk, 0, stream>>>(g1, w2h, w2l, h2, N);
    att_scores<<<(N + 255) / 256, blk, 0, stream>>>(h2, att_s2, att_d2, as2, ad2, N, 0);
    gat_agg1_sp<<<(N + 3) / 4, blk, 0, stream>>>(srcs, E, rowp, eid, as2, ad2, h2, bias2, g2, N);

    // ---- fusion MLP ----
    fusion_kernel<<<512, blk, 0, stream>>>(g2, tt, Wf1, bf1, Wf2, bf2, out, N);
}

// Round 12
// 728.535 us; speedup vs baseline: 1.0120x; 1.0120x over previous
//
#include <hip/hip_runtime.h>
#include <math.h>

#define HEADS1 4
#define HID 64
#define LSTM_H 32
#define IN_F 128
#define T_STEPS 50
#define NEG_SLOPE 0.2f
#define EPS_A 1e-16f

typedef __attribute__((ext_vector_type(8))) short short8;
typedef __attribute__((ext_vector_type(4))) float floatx4;
typedef __attribute__((ext_vector_type(4))) unsigned uint32x4;

// ---------- helpers ----------
// Single-instruction reciprocal (1 ulp). Without -ffast-math the compiler
// expands 1.0f/x to the ~12-inst IEEE div sequence. [r16: -42% on lstm]
__device__ __forceinline__ float frcp(float x) {
    float r;
    asm("v_rcp_f32 %0, %1" : "=v"(r) : "v"(x));
    return r;
}
__device__ __forceinline__ float sigf(float x) { return frcp(1.0f + __expf(-x)); }
__device__ __forceinline__ float tanhfast(float x) {
    float e = __expf(2.0f * x);
    return 1.0f - 2.0f * frcp(e + 1.0f);
}
__device__ __forceinline__ unsigned short f2bf(float f) {
    unsigned u = __float_as_uint(f);
    unsigned r = (u + 0x7FFFu + ((u >> 16) & 1u)) >> 16;
    return (unsigned short)r;
}
__device__ __forceinline__ float bf2f(unsigned short s) {
    return __uint_as_float(((unsigned)s) << 16);
}
// HW packed fp32->bf16 (2 values / instruction); no builtin on gfx950, inline asm.
__device__ __forceinline__ unsigned cvt_pk_bf16(float a, float b) {
    unsigned r;
    asm("v_cvt_pk_bf16_f32 %0, %1, %2" : "=v"(r) : "v"(a), "v"(b));
    return r;
}
__device__ __forceinline__ float lo16f(unsigned p) { return __uint_as_float(p << 16); }
__device__ __forceinline__ float hi16f(unsigned p) { return __uint_as_float(p & 0xffff0000u); }
__device__ __forceinline__ short8 bc8(uint32x4 v) { return __builtin_bit_cast(short8, v); }

// ---------- weight transpose+split prepack for MFMA GEMM ----------
template <int KK>
__global__ void prep_wt(const float* __restrict__ W, unsigned short* __restrict__ th,
                        unsigned short* __restrict__ tl, int total, int NC) {
    int i = blockIdx.x * 256 + threadIdx.x;
    if (i >= total) return;
    int n = i / KK, k = i - n * KK;
    float v = W[k * NC + n];
    unsigned short h = f2bf(v);
    th[i] = h;
    tl[i] = f2bf(v - bf2f(h));
}

// ---------- MFMA GEMM: C[M,NC] = A[M,K] @ B[K,NC], split-bf16 3-product ----
template <int K, int NC>
__global__ __launch_bounds__(256)
void gemm_mfma(const float* __restrict__ A, const unsigned short* __restrict__ Bth,
               const unsigned short* __restrict__ Btl, float* __restrict__ C, int M) {
    __shared__ float sA[128][44];            // 22.5 KB
    __shared__ unsigned short sBh[64][40];   // 5 KB
    __shared__ unsigned short sBl[64][40];   // 5 KB
    const int tid = threadIdx.x;
    const int wave = tid >> 6, lane = tid & 63;
    const int wr = wave >> 1, wc = wave & 1;
    const int row0 = blockIdx.x * 128;
    const int col0 = blockIdx.y * 64;
    const int l15 = lane & 15, l4 = lane >> 4;

    floatx4 acc[4][2];
#pragma unroll
    for (int rb = 0; rb < 4; rb++)
#pragma unroll
        for (int cb = 0; cb < 2; cb++) acc[rb][cb] = (floatx4){0.f, 0.f, 0.f, 0.f};

    for (int k0 = 0; k0 < K; k0 += 32) {
        __syncthreads();
#pragma unroll
        for (int q = 0; q < 4; q++) {
            int idx = q * 256 + tid;
            int row = idx >> 3, seg = idx & 7;
            int gr = row0 + row;
            float4 v = (gr < M) ? *(const float4*)&A[(size_t)gr * K + k0 + seg * 4]
                                : make_float4(0.f, 0.f, 0.f, 0.f);
            *(float4*)&sA[row][seg * 4] = v;
        }
        {
            int col = tid >> 2, seg = tid & 3;
            size_t gb = (size_t)(col0 + col) * K + k0 + seg * 8;
            *(short8*)&sBh[col][seg * 8] = *(const short8*)&Bth[gb];
            *(short8*)&sBl[col][seg * 8] = *(const short8*)&Btl[gb];
        }
        __syncthreads();

        short8 bh0 = *(const short8*)&sBh[wc * 32 + 0 + l15][l4 * 8];
        short8 bl0 = *(const short8*)&sBl[wc * 32 + 0 + l15][l4 * 8];
        short8 bh1 = *(const short8*)&sBh[wc * 32 + 16 + l15][l4 * 8];
        short8 bl1 = *(const short8*)&sBl[wc * 32 + 16 + l15][l4 * 8];

#pragma unroll
        for (int rb = 0; rb < 4; rb++) {
            int row = wr * 64 + rb * 16 + l15;
            floatx4 a0 = *(const floatx4*)&sA[row][l4 * 8 + 0];
            floatx4 a1 = *(const floatx4*)&sA[row][l4 * 8 + 4];
            unsigned p0 = cvt_pk_bf16(a0[0], a0[1]);
            unsigned p1 = cvt_pk_bf16(a0[2], a0[3]);
            unsigned p2 = cvt_pk_bf16(a1[0], a1[1]);
            unsigned p3 = cvt_pk_bf16(a1[2], a1[3]);
            uint32x4 hp = {p0, p1, p2, p3};
            short8 Ah = bc8(hp);
            unsigned q0 = cvt_pk_bf16(a0[0] - lo16f(p0), a0[1] - hi16f(p0));
            unsigned q1 = cvt_pk_bf16(a0[2] - lo16f(p1), a0[3] - hi16f(p1));
            unsigned q2 = cvt_pk_bf16(a1[0] - lo16f(p2), a1[1] - hi16f(p2));
            unsigned q3 = cvt_pk_bf16(a1[2] - lo16f(p3), a1[3] - hi16f(p3));
            uint32x4 lp = {q0, q1, q2, q3};
            short8 Al = bc8(lp);

            acc[rb][0] = __builtin_amdgcn_mfma_f32_16x16x32_bf16(Ah, bh0, acc[rb][0], 0, 0, 0);
            acc[rb][0] = __builtin_amdgcn_mfma_f32_16x16x32_bf16(Ah, bl0, acc[rb][0], 0, 0, 0);
            acc[rb][0] = __builtin_amdgcn_mfma_f32_16x16x32_bf16(Al, bh0, acc[rb][0], 0, 0, 0);
            acc[rb][1] = __builtin_amdgcn_mfma_f32_16x16x32_bf16(Ah, bh1, acc[rb][1], 0, 0, 0);
            acc[rb][1] = __builtin_amdgcn_mfma_f32_16x16x32_bf16(Ah, bl1, acc[rb][1], 0, 0, 0);
            acc[rb][1] = __builtin_amdgcn_mfma_f32_16x16x32_bf16(Al, bh1, acc[rb][1], 0, 0, 0);
        }
    }

#pragma unroll
    for (int rb = 0; rb < 4; rb++)
#pragma unroll
        for (int cb = 0; cb < 2; cb++)
#pragma unroll
            for (int q = 0; q < 4; q++) {
                int row = row0 + wr * 64 + rb * 16 + l4 * 4 + q;
                int col = col0 + wc * 32 + cb * 16 + l15;
                if (row < M) C[(size_t)row * NC + col] = acc[rb][cb][q];
            }
}

// ---------- attention scores ----------
__global__ void att_scores(const float* __restrict__ h, const float* __restrict__ att_s,
                           const float* __restrict__ att_d, float* __restrict__ as_,
                           float* __restrict__ ad_, int NH, int Hmask) {
    int i = blockIdx.x * blockDim.x + threadIdx.x;
    if (i >= NH) return;
    int hh = i & Hmask;
    const float* row = h + (size_t)i * HID;
    float s = 0.0f, d = 0.0f;
#pragma unroll 8
    for (int c = 0; c < HID; c++) {
        float v = row[c];
        s += v * att_s[hh * HID + c];
        d += v * att_d[hh * HID + c];
    }
    as_[i] = s;
    ad_[i] = d;
}

// ---------- CSR build ----------
__global__ void count_deg(const int* __restrict__ dsts, int E, int ET, int* __restrict__ cnt) {
    int e = blockIdx.x * blockDim.x + threadIdx.x;
    if (e >= ET) return;
    int d = (e < E) ? dsts[e] : (e - E);
    atomicAdd(&cnt[d], 1);
}

__global__ void scan1(const int* __restrict__ cnt, int* __restrict__ rowp,
                      int* __restrict__ bsum, int N) {
    __shared__ int tmp[256];
    int i = blockIdx.x * 256 + threadIdx.x;
    int v = (i < N) ? cnt[i] : 0;
    tmp[threadIdx.x] = v;
    __syncthreads();
    for (int off = 1; off < 256; off <<= 1) {
        int t = (threadIdx.x >= (unsigned)off) ? tmp[threadIdx.x - off] : 0;
        __syncthreads();
        tmp[threadIdx.x] += t;
        __syncthreads();
    }
    if (i < N) rowp[i] = tmp[threadIdx.x] - v;
    if (threadIdx.x == 255) bsum[blockIdx.x] = tmp[255];
}

__global__ void scan2(int* __restrict__ bsum, int nb) {
    __shared__ int tmp[256];
    int v = (threadIdx.x < (unsigned)nb) ? bsum[threadIdx.x] : 0;
    tmp[threadIdx.x] = v;
    __syncthreads();
    for (int off = 1; off < 256; off <<= 1) {
        int t = (threadIdx.x >= (unsigned)off) ? tmp[threadIdx.x - off] : 0;
        __syncthreads();
        tmp[threadIdx.x] += t;
        __syncthreads();
    }
    if (threadIdx.x < (unsigned)nb) bsum[threadIdx.x] = tmp[threadIdx.x] - v;
}

__global__ void scan3(int* __restrict__ rowp, const int* __restrict__ bsum, int N, int ET) {
    int i = blockIdx.x * 256 + threadIdx.x;
    if (i < N) rowp[i] += bsum[blockIdx.x];
    if (i == 0) rowp[N] = ET;
}

__global__ void scatter_edges(const int* __restrict__ dsts, int E, int ET,
                              const int* __restrict__ rowp, int* __restrict__ cursor,
                              int* __restrict__ eid) {
    int e = blockIdx.x * blockDim.x + threadIdx.x;
    if (e >= ET) return;
    int d = (e < E) ? dsts[e] : (e - E);
    int pos = atomicAdd(&cursor[d], 1);
    eid[rowp[d] + pos] = e;
}

// ---------- GAT layer-1 aggregation: single pass, one wave per dst, 4 heads ----------
__global__ __launch_bounds__(256)
void gat_agg4_sp(const int* __restrict__ srcs, int E,
                 const int* __restrict__ rowp, const int* __restrict__ eid,
                 const float* __restrict__ as_, const float* __restrict__ ad_,
                 const float* __restrict__ hfeat, const float* __restrict__ bias,
                 float* __restrict__ g, int N) {
    __shared__ float s_alpha[4][64][4];
    const int wave = threadIdx.x >> 6;
    const int lane = threadIdx.x & 63;
    const int head = lane >> 4;
    const int dst = blockIdx.x * 4 + wave;
    if (dst >= N) return;
    const int start = rowp[dst], end = rowp[dst + 1];
    const float4 adv = ((const float4*)ad_)[dst];
    const float4* h4 = (const float4*)hfeat;

    float4 dsum = make_float4(0.f, 0.f, 0.f, 0.f);
    float4 acc  = make_float4(0.f, 0.f, 0.f, 0.f);

    for (int i0 = start; i0 < end; i0 += 64) {
        int cnt = min(64, end - i0);
        int i = i0 + lane;
        int s = 0;
        if (i < end) {
            int e = eid[i];
            s = (e < E) ? srcs[e] : (e - E);
            float4 a = ((const float4*)as_)[s];
            float tx, ex;
            tx = a.x + adv.x; tx = (tx > 0.f) ? tx : NEG_SLOPE * tx; ex = __expf(tx);
            dsum.x += ex; s_alpha[wave][lane][0] = ex;
            tx = a.y + adv.y; tx = (tx > 0.f) ? tx : NEG_SLOPE * tx; ex = __expf(tx);
            dsum.y += ex; s_alpha[wave][lane][1] = ex;
            tx = a.z + adv.z; tx = (tx > 0.f) ? tx : NEG_SLOPE * tx; ex = __expf(tx);
            dsum.z += ex; s_alpha[wave][lane][2] = ex;
            tx = a.w + adv.w; tx = (tx > 0.f) ? tx : NEG_SLOPE * tx; ex = __expf(tx);
            dsum.w += ex; s_alpha[wave][lane][3] = ex;
        }
        __builtin_amdgcn_wave_barrier();
#pragma unroll 4
        for (int k = 0; k < cnt; k++) {
            float a_k = s_alpha[wave][k][head];   // 16-lane broadcast read
            int   s_k = __shfl(s, k);
            float4 hv = h4[(size_t)s_k * 64 + lane];
            acc.x += a_k * hv.x; acc.y += a_k * hv.y;
            acc.z += a_k * hv.z; acc.w += a_k * hv.w;
        }
        __builtin_amdgcn_wave_barrier();
    }
#pragma unroll
    for (int mk = 32; mk >= 1; mk >>= 1) {
        dsum.x += __shfl_xor(dsum.x, mk);
        dsum.y += __shfl_xor(dsum.y, mk);
        dsum.z += __shfl_xor(dsum.z, mk);
        dsum.w += __shfl_xor(dsum.w, mk);
    }
    float den = (head == 0) ? dsum.x : (head == 1) ? dsum.y : (head == 2) ? dsum.z : dsum.w;
    float inv = 1.0f / (den + EPS_A);
    float4 b4 = ((const float4*)bias)[lane];
    float4 r;
    r.x = acc.x * inv + b4.x; r.x = (r.x > 0.f) ? r.x : __expf(r.x) - 1.f;
    r.y = acc.y * inv + b4.y; r.y = (r.y > 0.f) ? r.y : __expf(r.y) - 1.f;
    r.z = acc.z * inv + b4.z; r.z = (r.z > 0.f) ? r.z : __expf(r.z) - 1.f;
    r.w = acc.w * inv + b4.w; r.w = (r.w > 0.f) ? r.w : __expf(r.w) - 1.f;
    ((float4*)g)[(size_t)dst * 64 + lane] = r;
}

// ---------- GAT layer-2 aggregation: single pass, one wave per dst, H=1 ----------
__global__ __launch_bounds__(256)
void gat_agg1_sp(const int* __restrict__ srcs, int E,
                 const int* __restrict__ rowp, const int* __restrict__ eid,
                 const float* __restrict__ as_, const float* __restrict__ ad_,
                 const float* __restrict__ hfeat, const float* __restrict__ bias,
                 float* __restrict__ g, int N) {
    __shared__ float s_alpha[4][64];
    const int wave = threadIdx.x >> 6;
    const int lane = threadIdx.x & 63;
    const int dst = blockIdx.x * 4 + wave;
    if (dst >= N) return;
    const int start = rowp[dst], end = rowp[dst + 1];
    const float adv = ad_[dst];

    float dsum = 0.0f, acc = 0.0f;
    for (int i0 = start; i0 < end; i0 += 64) {
        int cnt = min(64, end - i0);
        int i = i0 + lane;
        int s = 0;
        if (i < end) {
            int e = eid[i];
            s = (e < E) ? srcs[e] : (e - E);
            float t = as_[s] + adv;
            t = (t > 0.f) ? t : NEG_SLOPE * t;
            float ex = __expf(t);
            dsum += ex;
            s_alpha[wave][lane] = ex;
        }
        __builtin_amdgcn_wave_barrier();
#pragma unroll 4
        for (int k = 0; k < cnt; k++) {
            float a_k = s_alpha[wave][k];         // full-wave broadcast read
            int   s_k = __shfl(s, k);
            acc += a_k * hfeat[(size_t)s_k * 64 + lane];
        }
        __builtin_amdgcn_wave_barrier();
    }
#pragma unroll
    for (int mk = 32; mk >= 1; mk >>= 1) dsum += __shfl_xor(dsum, mk);
    g[(size_t)dst * 64 + lane] = acc / (dsum + EPS_A) + bias[lane];
}

// ---------- LSTM weight prepack (runs once, 1 block) ----------
// Layout [kk][which][sub][lane]: fragment for gate kk (i,f,g,o), type which
// (B2/BH/BL), unit-half sub.
__global__ void prep_wsplit(const float* __restrict__ Wih, const float* __restrict__ Whh,
                            const float* __restrict__ bih, const float* __restrict__ bhh,
                            uint32x4* __restrict__ wsp) {
    const int tid = threadIdx.x;          // 0..511
    const int kk = tid >> 7, sub = (tid >> 6) & 1, lane = tid & 63;
    const int grp = lane >> 4, col = lane & 15;
    const int krow = grp * 8;
    const int n = (sub + kk * 2) * 16 + col;
    float w[8];
    *(float4*)&w[0] = *(const float4*)&Whh[n * 32 + krow + 0];
    *(float4*)&w[4] = *(const float4*)&Whh[n * 32 + krow + 4];
    unsigned hi[8], lo[8];
#pragma unroll
    for (int j = 0; j < 8; j++) {
        unsigned short hs = f2bf(w[j]);
        hi[j] = hs;
        lo[j] = f2bf(w[j] - bf2f(hs));
    }
    uint32x4 BH = {hi[0] | (hi[1] << 16), hi[2] | (hi[3] << 16),
                   hi[4] | (hi[5] << 16), hi[6] | (hi[7] << 16)};
    uint32x4 BL = {lo[0] | (lo[1] << 16), lo[2] | (lo[3] << 16),
                   lo[4] | (lo[5] << 16), lo[6] | (lo[7] << 16)};
    float wi0 = Wih[n * 3 + 0], wi1 = Wih[n * 3 + 1], wi2 = Wih[n * 3 + 2];
    float bb = bih[n] + bhh[n];
    unsigned h0 = f2bf(wi0), h1 = f2bf(wi1), h2 = f2bf(wi2), hb = f2bf(bb);
    uint32x4 B2 = {0u, 0u, 0u, 0u};
    if (grp == 0) {
        unsigned bl_ = f2bf(bb - bf2f((unsigned short)hb));
        B2[0] = h0 | (h1 << 16); B2[1] = h2 | (hb << 16);
        B2[2] = h0 | (h1 << 16); B2[3] = h2 | (bl_ << 16);
    } else if (grp == 1) {
        unsigned l0 = f2bf(wi0 - bf2f((unsigned short)h0));
        unsigned l1 = f2bf(wi1 - bf2f((unsigned short)h1));
        unsigned l2 = f2bf(wi2 - bf2f((unsigned short)h2));
        B2[0] = l0 | (l1 << 16); B2[1] = l2;
    }
    wsp[((kk * 3 + 0) * 2 + sub) * 64 + lane] = B2;
    wsp[((kk * 3 + 1) * 2 + sub) * 64 + lane] = BH;
    wsp[((kk * 3 + 2) * 2 + sub) * 64 + lane] = BL;
}

// ---------- LSTM via MFMA (split-bf16), round-20: pair-split, fit-the-88 ----
// r19 post-mortem finally localized the wall: VGPR_Count=88 vs a ~140-reg
// live set (24 frags = 96 alone) => the allocator spilled ~half the fragments
// to scratch, and the per-ts restores (~200-400cy each, scheduler places them
// right before each MFMA group so nothing hides them) ARE the ~9K-cycle/ts
// wall. 88 is also the most the allocator has ever granted (52/52/52/52/88)
// -- and it happened with a 256-thread block + plain __launch_bounds__(256).
// Fix: shrink the live set to fit 88. Pair-split gates (12 frags = 48 VGPR;
// + A-frags 12 + state 8 + x/addr ~15 = ~83) in 256-thr blocks = 2 pairs,
// 32 nodes/block, grid 1563. h via per-pair LDS ping-pong + 1 syncthreads
// (couples 2 pairs; r19 proved barrier coupling is ~free). x from global
// with 1-step prefetch (r13/r18 proved slab vs direct is neutral).
// VERIFY: VGPR >= 80 (52-64 => allocator re-spilled => pivot to LDS frags);
// dur ~80-130us; WRITE_SIZE 6250.
__global__ __launch_bounds__(256)
void lstm_mfma(const float* __restrict__ seq, const uint32x4* __restrict__ wsp,
               float* __restrict__ t_out, int N) {
    __shared__ float s_h[2][2][16][36];     // [pair][pingpong][node][unit+pad] 9.2 KB

    const int tid  = threadIdx.x;
    const int wave = tid >> 6, lane = tid & 63;
    const int pair = wave >> 1, sub = wave & 1;
    const int grp  = lane >> 4, col = lane & 15;
    const int node0 = blockIdx.x * 32 + pair * 16;

    // ---- 12 weight fragments: coalesced 16B loads, no arithmetic ----
#define LF(KK, W) wsp[(((KK) * 3 + (W)) * 2 + sub) * 64 + lane]
    uint32x4 B2_0 = LF(0, 0), BH_0 = LF(0, 1), BL_0 = LF(0, 2);
    uint32x4 B2_1 = LF(1, 0), BH_1 = LF(1, 1), BL_1 = LF(1, 2);
    uint32x4 B2_2 = LF(2, 0), BH_2 = LF(2, 1), BL_2 = LF(2, 2);
    uint32x4 B2_3 = LF(3, 0), BH_3 = LF(3, 1), BL_3 = LF(3, 2);
#undef LF
    asm volatile("" : "+v"(B2_0), "+v"(BH_0), "+v"(BL_0),
                      "+v"(B2_1), "+v"(BH_1), "+v"(BL_1),
                      "+v"(B2_2), "+v"(BH_2), "+v"(BL_2),
                      "+v"(B2_3), "+v"(BH_3), "+v"(BL_3));

    for (int i = tid; i < 2 * 2 * 16 * 36; i += 256) ((float*)s_h)[i] = 0.0f;
    __syncthreads();

    float cst0 = 0.f, cst1 = 0.f, cst2 = 0.f, cst3 = 0.f;
    float hn0 = 0.f, hn1 = 0.f, hn2 = 0.f, hn3 = 0.f;
    const floatx4 zac = {0.f, 0.f, 0.f, 0.f};

    const int nodeX = node0 + col;
    const bool vx = (nodeX < N) && (grp < 2);
    const bool g0 = (grp == 0);
    const float* xp = seq + (size_t)nodeX * (T_STEPS * 3);

    // x for t=0
    float xv0 = vx ? xp[0] : 0.0f;
    float xv1 = vx ? xp[1] : 0.0f;
    float xv2 = vx ? xp[2] : 0.0f;

#pragma unroll 1
    for (int t = 0; t < T_STEPS; t++) {
        // ---- A2: x hi/lo + ones in K-slots (grp0: k'0-7, grp1: k'8-10) ----
        unsigned w0 = cvt_pk_bf16(xv0, xv1);
        unsigned w1 = cvt_pk_bf16(xv2, g0 ? 1.0f : 0.0f);
        float e0 = xv0 - lo16f(w0);
        float e1 = xv1 - hi16f(w0);
        float e2 = xv2 - lo16f(w1);
        unsigned w2 = g0 ? cvt_pk_bf16(e0, e1) : 0u;
        unsigned w3 = g0 ? cvt_pk_bf16(e2, 1.0f) : 0u;
        uint32x4 a2p = {w0, w1, w2, w3};
        short8 A2 = bc8(a2p);

        // ---- A (h) hi/lo from ping-pong LDS (prev buffer; t=0 reads zeros) ----
        const float* hr = &s_h[pair][(t + 1) & 1][col][grp * 8];
        floatx4 h0 = *(const floatx4*)&hr[0];
        floatx4 h1 = *(const floatx4*)&hr[4];
        unsigned p0 = cvt_pk_bf16(h0[0], h0[1]);
        unsigned p1 = cvt_pk_bf16(h0[2], h0[3]);
        unsigned p2 = cvt_pk_bf16(h1[0], h1[1]);
        unsigned p3 = cvt_pk_bf16(h1[2], h1[3]);
        uint32x4 hip = {p0, p1, p2, p3};
        short8 Ahi = bc8(hip);
        unsigned q0 = cvt_pk_bf16(h0[0] - lo16f(p0), h0[1] - hi16f(p0));
        unsigned q1 = cvt_pk_bf16(h0[2] - lo16f(p1), h0[3] - hi16f(p1));
        unsigned q2 = cvt_pk_bf16(h1[0] - lo16f(p2), h1[1] - hi16f(p2));
        unsigned q3 = cvt_pk_bf16(h1[2] - lo16f(p3), h1[3] - hi16f(p3));
        uint32x4 lop = {q0, q1, q2, q3};
        short8 Alo = bc8(lop);

        // ---- prefetch next x (clamped offset; hidden under MFMAs+gates) ----
        {
            int tn = (t + 1 < T_STEPS) ? (t + 1) : t;
            xv0 = vx ? xp[tn * 3 + 0] : 0.0f;
            xv1 = vx ? xp[tn * 3 + 1] : 0.0f;
            xv2 = vx ? xp[tn * 3 + 2] : 0.0f;
        }

        // ---- this wave's 4 gate-blocks x 4 MFMAs; all operands in registers ----
        floatx4 d0 = __builtin_amdgcn_mfma_f32_16x16x32_bf16(A2, bc8(B2_0), zac, 0, 0, 0);
        d0 = __builtin_amdgcn_mfma_f32_16x16x32_bf16(Alo, bc8(BH_0), d0, 0, 0, 0);
        d0 = __builtin_amdgcn_mfma_f32_16x16x32_bf16(Ahi, bc8(BL_0), d0, 0, 0, 0);
        d0 = __builtin_amdgcn_mfma_f32_16x16x32_bf16(Ahi, bc8(BH_0), d0, 0, 0, 0);
        floatx4 d1 = __builtin_amdgcn_mfma_f32_16x16x32_bf16(A2, bc8(B2_1), zac, 0, 0, 0);
        d1 = __builtin_amdgcn_mfma_f32_16x16x32_bf16(Alo, bc8(BH_1), d1, 0, 0, 0);
        d1 = __builtin_amdgcn_mfma_f32_16x16x32_bf16(Ahi, bc8(BL_1), d1, 0, 0, 0);
        d1 = __builtin_amdgcn_mfma_f32_16x16x32_bf16(Ahi, bc8(BH_1), d1, 0, 0, 0);
        floatx4 d2 = __builtin_amdgcn_mfma_f32_16x16x32_bf16(A2, bc8(B2_2), zac, 0, 0, 0);
        d2 = __builtin_amdgcn_mfma_f32_16x16x32_bf16(Alo, bc8(BH_2), d2, 0, 0, 0);
        d2 = __builtin_amdgcn_mfma_f32_16x16x32_bf16(Ahi, bc8(BL_2), d2, 0, 0, 0);
        d2 = __builtin_amdgcn_mfma_f32_16x16x32_bf16(Ahi, bc8(BH_2), d2, 0, 0, 0);
        floatx4 d3 = __builtin_amdgcn_mfma_f32_16x16x32_bf16(A2, bc8(B2_3), zac, 0, 0, 0);
        d3 = __builtin_amdgcn_mfma_f32_16x16x32_bf16(Alo, bc8(BH_3), d3, 0, 0, 0);
        d3 = __builtin_amdgcn_mfma_f32_16x16x32_bf16(Ahi, bc8(BL_3), d3, 0, 0, 0);
        d3 = __builtin_amdgcn_mfma_f32_16x16x32_bf16(Ahi, bc8(BH_3), d3, 0, 0, 0);

        // ---- gates: d0=i, d1=f, d2=g, d3=o; per-q unrolled, named state ----
        {
            float ig, fg, gv, og;
            ig = sigf(d0[0]); fg = sigf(d1[0]); gv = tanhfast(d2[0]); og = sigf(d3[0]);
            cst0 = fg * cst0 + ig * gv; hn0 = og * tanhfast(cst0);
            ig = sigf(d0[1]); fg = sigf(d1[1]); gv = tanhfast(d2[1]); og = sigf(d3[1]);
            cst1 = fg * cst1 + ig * gv; hn1 = og * tanhfast(cst1);
            ig = sigf(d0[2]); fg = sigf(d1[2]); gv = tanhfast(d2[2]); og = sigf(d3[2]);
            cst2 = fg * cst2 + ig * gv; hn2 = og * tanhfast(cst2);
            ig = sigf(d0[3]); fg = sigf(d1[3]); gv = tanhfast(d2[3]); og = sigf(d3[3]);
            cst3 = fg * cst3 + ig * gv; hn3 = og * tanhfast(cst3);
        }

        // ---- h writeback to ping-pong buffer, then barrier (2 pairs coupled) ----
        float* hw = &s_h[pair][t & 1][4 * grp][sub * 16 + col];
        hw[0 * 36] = hn0; hw[1 * 36] = hn1; hw[2 * 36] = hn2; hw[3 * 36] = hn3;
        __syncthreads();
    }

    {
        int node = node0 + 4 * grp;
        const int c = sub * 16 + col;
        if (node + 0 < N) t_out[(size_t)(node + 0) * LSTM_H + c] = hn0;
        if (node + 1 < N) t_out[(size_t)(node + 1) * LSTM_H + c] = hn1;
        if (node + 2 < N) t_out[(size_t)(node + 2) * LSTM_H + c] = hn2;
        if (node + 3 < N) t_out[(size_t)(node + 3) * LSTM_H + c] = hn3;
    }
}

// ---------- fusion MLP ----------
__global__ void fusion_kernel(const float* __restrict__ g2, const float* __restrict__ tt,
                              const float* __restrict__ Wf1, const float* __restrict__ bf1,
                              const float* __restrict__ Wf2, const float* __restrict__ bf2,
                              float* __restrict__ out, int N) {
    __shared__ float sW[96 * 64];
    __shared__ float sb1[64];
    __shared__ float sW2[128];
    for (int i = threadIdx.x; i < 96 * 64; i += 256) sW[i] = Wf1[i];
    if (threadIdx.x < 64) sb1[threadIdx.x] = bf1[threadIdx.x];
    if (threadIdx.x < 128) sW2[threadIdx.x] = Wf2[threadIdx.x];
    __syncthreads();
    const int wave = threadIdx.x >> 6;
    const int lane = threadIdx.x & 63;
    for (int n = blockIdx.x * 4 + wave; n < N; n += gridDim.x * 4) {
        const float* gn = g2 + (size_t)n * 64;
        const float* tn = tt + (size_t)n * 32;
        float acc = sb1[lane];
#pragma unroll 8
        for (int k = 0; k < 64; k++) acc += gn[k] * sW[k * 64 + lane];
#pragma unroll 8
        for (int k = 0; k < 32; k++) acc += tn[k] * sW[(64 + k) * 64 + lane];
        acc = fmaxf(acc, 0.0f);
        float o0 = acc * sW2[lane * 2 + 0];
        float o1 = acc * sW2[lane * 2 + 1];
#pragma unroll
    for (int mk = 32; mk >= 1; mk >>= 1) {
            o0 += __shfl_xor(o0, mk);
            o1 += __shfl_xor(o1, mk);
        }
        if (lane == 0) {
            out[(size_t)n * 2 + 0] = o0 + bf2[0];
            out[(size_t)n * 2 + 1] = o1 + bf2[1];
        }
    }
}

extern "C" void kernel_launch(void* const* d_in, const int* in_sizes, int n_in,
                              void* d_out, int out_size, void* d_ws, size_t ws_size,
                              hipStream_t stream) {
    const float* x      = (const float*)d_in[0];
    const int*   eidx   = (const int*)d_in[1];
    const float* seq    = (const float*)d_in[2];
    const float* W1     = (const float*)d_in[3];
    const float* att_s1 = (const float*)d_in[4];
    const float* att_d1 = (const float*)d_in[5];
    const float* bias1  = (const float*)d_in[6];
    const float* W2     = (const float*)d_in[7];
    const float* att_s2 = (const float*)d_in[8];
    const float* att_d2 = (const float*)d_in[9];
    const float* bias2  = (const float*)d_in[10];
    const float* Wih    = (const float*)d_in[11];
    const float* Whh    = (const float*)d_in[12];
    const float* bih    = (const float*)d_in[13];
    const float* bhh    = (const float*)d_in[14];
    const float* Wf1    = (const float*)d_in[15];
    const float* bf1    = (const float*)d_in[16];
    const float* Wf2    = (const float*)d_in[17];
    const float* bf2    = (const float*)d_in[18];
    float* out = (float*)d_out;

    const int N  = in_sizes[0] / IN_F;   // 50000
    const int E  = in_sizes[1] / 2;      // 800000
    const int ET = E + N;
    const int* srcs = eidx;
    const int* dsts = eidx + E;

    // workspace layout
    float* fws = (float*)d_ws;
    size_t o = 0;
    float* h1  = fws + o; o += (size_t)N * 256;
    float* g1  = fws + o; o += (size_t)N * 256;
    float* as1 = fws + o; o += (size_t)N * 4;
    float* ad1 = fws + o; o += (size_t)N * 4;
    int* cnt    = (int*)(fws + o);
    int* rowp   = cnt + N;
    int* cursor = rowp + N + 1;
    int* eid    = cursor + N;
    int* bsum   = eid + ET;
    // prepacked LSTM weight fragments (24.5 KB, 16B-aligned)
    uintptr_t wp_ = (uintptr_t)(bsum + 512);
    wp_ = (wp_ + 15) & ~(uintptr_t)15;
    uint32x4* wsp = (uint32x4*)wp_;
    // prepacked transposed GEMM weights (hi/lo): W1t 2x32768, W2t 2x16384 shorts
    unsigned short* w1h = (unsigned short*)(wsp + 1536);
    unsigned short* w1l = w1h + 32768;
    unsigned short* w2h = w1l + 32768;
    unsigned short* w2l = w2h + 16384;
    // layer-2 / LSTM aliases (h1 region dead after layer-1 aggregation)
    float* h2 = h1;                      // N*64
    float* g2 = h1 + (size_t)N * 64;     // N*64
    float* tt = h1 + (size_t)N * 128;    // N*32
    float* as2 = as1; float* ad2 = ad1;

    const int nTiles = (N + 255) / 256;
    dim3 blk(256);

    // ---- CSR build ----
    hipMemsetAsync(cnt, 0, (size_t)N * sizeof(int), stream);
    hipMemsetAsync(cursor, 0, (size_t)N * sizeof(int), stream);
    count_deg<<<(ET + 255) / 256, blk, 0, stream>>>(dsts, E, ET, cnt);
    scan1<<<nTiles, blk, 0, stream>>>(cnt, rowp, bsum, N);
    scan2<<<1, blk, 0, stream>>>(bsum, nTiles);
    scan3<<<(N + 256) / 256, blk, 0, stream>>>(rowp, bsum, N, ET);
    scatter_edges<<<(ET + 255) / 256, blk, 0, stream>>>(dsts, E, ET, rowp, cursor, eid);

    // ---- weight prepacks (tiny, once) ----
    prep_wsplit<<<1, 512, 0, stream>>>(Wih, Whh, bih, bhh, wsp);
    prep_wt<128><<<(32768 + 255) / 256, blk, 0, stream>>>(W1, w1h, w1l, 32768, 256);
    prep_wt<256><<<(16384 + 255) / 256, blk, 0, stream>>>(W2, w2h, w2l, 16384, 64);

    // ---- GAT layer 1 (MFMA split-bf16 GEMM) ----
    gemm_mfma<128, 256><<<dim3((N + 127) / 128, 4), blk, 0, stream>>>(x, w1h, w1l, h1, N);
    att_scores<<<(N * 4 + 255) / 256, blk, 0, stream>>>(h1, att_s1, att_d1, as1, ad1, N * 4, 3);
    gat_agg4_sp<<<(N + 3) / 4, blk, 0, stream>>>(srcs, E, rowp, eid, as1, ad1, h1, bias1, g1, N);

    // ---- LSTM (MFMA; pair-split, 12-frag live set fits the 88-reg grant) ----
    lstm_mfma<<<(N + 31) / 32, dim3(256), 0, stream>>>(seq, wsp, tt, N);

    // ---- GAT layer 2 (MFMA split-bf16 GEMM) ----
    gemm_mfma<256, 64><<<dim3((N + 127) / 128, 1), blk, 0, stream>>>(g1, w2h, w2l, h2, N);
    att_scores<<<(N + 255) / 256, blk, 0, stream>>>(h2, att_s2, att_d2, as2, ad2, N, 0);
    gat_agg1_sp<<<(N + 3) / 4, blk, 0, stream>>>(srcs, E, rowp, eid, as2, ad2, h2, bias2, g2, N);

    // ---- fusion MLP ----
    fusion_kernel<<<512, blk, 0, stream>>>(g2, tt, Wf1, bf1, Wf2, bf2, out, N);
}

// Round 14
// 699.294 us; speedup vs baseline: 1.0543x; 1.0418x over previous
//
#include <hip/hip_runtime.h>
#include <math.h>

#define HEADS1 4
#define HID 64
#define LSTM_H 32
#define IN_F 128
#define T_STEPS 50
#define NEG_SLOPE 0.2f
#define EPS_A 1e-16f

typedef __attribute__((ext_vector_type(8))) short short8;
typedef __attribute__((ext_vector_type(4))) float floatx4;
typedef __attribute__((ext_vector_type(4))) unsigned uint32x4;

// ---------- helpers ----------
__device__ __forceinline__ float frcp(float x) {
    float r;
    asm("v_rcp_f32 %0, %1" : "=v"(r) : "v"(x));
    return r;
}
__device__ __forceinline__ float sigf(float x) { return frcp(1.0f + __expf(-x)); }
__device__ __forceinline__ float tanhfast(float x) {
    float e = __expf(2.0f * x);
    return 1.0f - 2.0f * frcp(e + 1.0f);
}
__device__ __forceinline__ unsigned short f2bf(float f) {
    unsigned u = __float_as_uint(f);
    unsigned r = (u + 0x7FFFu + ((u >> 16) & 1u)) >> 16;
    return (unsigned short)r;
}
__device__ __forceinline__ float bf2f(unsigned short s) {
    return __uint_as_float(((unsigned)s) << 16);
}
__device__ __forceinline__ unsigned cvt_pk_bf16(float a, float b) {
    unsigned r;
    asm("v_cvt_pk_bf16_f32 %0, %1, %2" : "=v"(r) : "v"(a), "v"(b));
    return r;
}
__device__ __forceinline__ float lo16f(unsigned p) { return __uint_as_float(p << 16); }
__device__ __forceinline__ float hi16f(unsigned p) { return __uint_as_float(p & 0xffff0000u); }
__device__ __forceinline__ short8 bc8(uint32x4 v) { return __builtin_bit_cast(short8, v); }

// ---------- weight transpose+split prepack for MFMA GEMM ----------
template <int KK>
__global__ void prep_wt(const float* __restrict__ W, unsigned short* __restrict__ th,
                        unsigned short* __restrict__ tl, int total, int NC) {
    int i = blockIdx.x * 256 + threadIdx.x;
    if (i >= total) return;
    int n = i / KK, k = i - n * KK;
    float v = W[k * NC + n];
    unsigned short h = f2bf(v);
    th[i] = h;
    tl[i] = f2bf(v - bf2f(h));
}

// ---------- MFMA GEMM: C[M,NC] = A[M,K] @ B[K,NC], split-bf16 3-product ----
template <int K, int NC>
__global__ __launch_bounds__(256)
void gemm_mfma(const float* __restrict__ A, const unsigned short* __restrict__ Bth,
               const unsigned short* __restrict__ Btl, float* __restrict__ C, int M) {
    __shared__ float sA[128][44];            // 22.5 KB
    __shared__ unsigned short sBh[64][40];   // 5 KB
    __shared__ unsigned short sBl[64][40];   // 5 KB
    const int tid = threadIdx.x;
    const int wave = tid >> 6, lane = tid & 63;
    const int wr = wave >> 1, wc = wave & 1;
    const int row0 = blockIdx.x * 128;
    const int col0 = blockIdx.y * 64;
    const int l15 = lane & 15, l4 = lane >> 4;

    floatx4 acc[4][2];
#pragma unroll
    for (int rb = 0; rb < 4; rb++)
#pragma unroll
        for (int cb = 0; cb < 2; cb++) acc[rb][cb] = (floatx4){0.f, 0.f, 0.f, 0.f};

    for (int k0 = 0; k0 < K; k0 += 32) {
        __syncthreads();
#pragma unroll
        for (int q = 0; q < 4; q++) {
            int idx = q * 256 + tid;
            int row = idx >> 3, seg = idx & 7;
            int gr = row0 + row;
            float4 v = (gr < M) ? *(const float4*)&A[(size_t)gr * K + k0 + seg * 4]
                                : make_float4(0.f, 0.f, 0.f, 0.f);
            *(float4*)&sA[row][seg * 4] = v;
        }
        {
            int col = tid >> 2, seg = tid & 3;
            size_t gb = (size_t)(col0 + col) * K + k0 + seg * 8;
            *(short8*)&sBh[col][seg * 8] = *(const short8*)&Bth[gb];
            *(short8*)&sBl[col][seg * 8] = *(const short8*)&Btl[gb];
        }
        __syncthreads();

        short8 bh0 = *(const short8*)&sBh[wc * 32 + 0 + l15][l4 * 8];
        short8 bl0 = *(const short8*)&sBl[wc * 32 + 0 + l15][l4 * 8];
        short8 bh1 = *(const short8*)&sBh[wc * 32 + 16 + l15][l4 * 8];
        short8 bl1 = *(const short8*)&sBl[wc * 32 + 16 + l15][l4 * 8];

#pragma unroll
        for (int rb = 0; rb < 4; rb++) {
            int row = wr * 64 + rb * 16 + l15;
            floatx4 a0 = *(const floatx4*)&sA[row][l4 * 8 + 0];
            floatx4 a1 = *(const floatx4*)&sA[row][l4 * 8 + 4];
            unsigned p0 = cvt_pk_bf16(a0[0], a0[1]);
            unsigned p1 = cvt_pk_bf16(a0[2], a0[3]);
            unsigned p2 = cvt_pk_bf16(a1[0], a1[1]);
            unsigned p3 = cvt_pk_bf16(a1[2], a1[3]);
            uint32x4 hp = {p0, p1, p2, p3};
            short8 Ah = bc8(hp);
            unsigned q0 = cvt_pk_bf16(a0[0] - lo16f(p0), a0[1] - hi16f(p0));
            unsigned q1 = cvt_pk_bf16(a0[2] - lo16f(p1), a0[3] - hi16f(p1));
            unsigned q2 = cvt_pk_bf16(a1[0] - lo16f(p2), a1[1] - hi16f(p2));
            unsigned q3 = cvt_pk_bf16(a1[2] - lo16f(p3), a1[3] - hi16f(p3));
            uint32x4 lp = {q0, q1, q2, q3};
            short8 Al = bc8(lp);

            acc[rb][0] = __builtin_amdgcn_mfma_f32_16x16x32_bf16(Ah, bh0, acc[rb][0], 0, 0, 0);
            acc[rb][0] = __builtin_amdgcn_mfma_f32_16x16x32_bf16(Ah, bl0, acc[rb][0], 0, 0, 0);
            acc[rb][0] = __builtin_amdgcn_mfma_f32_16x16x32_bf16(Al, bh0, acc[rb][0], 0, 0, 0);
            acc[rb][1] = __builtin_amdgcn_mfma_f32_16x16x32_bf16(Ah, bh1, acc[rb][1], 0, 0, 0);
            acc[rb][1] = __builtin_amdgcn_mfma_f32_16x16x32_bf16(Ah, bl1, acc[rb][1], 0, 0, 0);
            acc[rb][1] = __builtin_amdgcn_mfma_f32_16x16x32_bf16(Al, bh1, acc[rb][1], 0, 0, 0);
        }
    }

#pragma unroll
    for (int rb = 0; rb < 4; rb++)
#pragma unroll
        for (int cb = 0; cb < 2; cb++)
#pragma unroll
            for (int q = 0; q < 4; q++) {
                int row = row0 + wr * 64 + rb * 16 + l4 * 4 + q;
                int col = col0 + wc * 32 + cb * 16 + l15;
                if (row < M) C[(size_t)row * NC + col] = acc[rb][cb][q];
            }
}

// ---------- attention scores ----------
__global__ void att_scores(const float* __restrict__ h, const float* __restrict__ att_s,
                           const float* __restrict__ att_d, float* __restrict__ as_,
                           float* __restrict__ ad_, int NH, int Hmask) {
    int i = blockIdx.x * blockDim.x + threadIdx.x;
    if (i >= NH) return;
    int hh = i & Hmask;
    const float* row = h + (size_t)i * HID;
    float s = 0.0f, d = 0.0f;
#pragma unroll 8
    for (int c = 0; c < HID; c++) {
        float v = row[c];
        s += v * att_s[hh * HID + c];
        d += v * att_d[hh * HID + c];
    }
    as_[i] = s;
    ad_[i] = d;
}

// ---------- CSR build ----------
__global__ void count_deg(const int* __restrict__ dsts, int E, int ET, int* __restrict__ cnt) {
    int e = blockIdx.x * blockDim.x + threadIdx.x;
    if (e >= ET) return;
    int d = (e < E) ? dsts[e] : (e - E);
    atomicAdd(&cnt[d], 1);
}

__global__ void scan1(const int* __restrict__ cnt, int* __restrict__ rowp,
                      int* __restrict__ bsum, int N) {
    __shared__ int tmp[256];
    int i = blockIdx.x * 256 + threadIdx.x;
    int v = (i < N) ? cnt[i] : 0;
    tmp[threadIdx.x] = v;
    __syncthreads();
    for (int off = 1; off < 256; off <<= 1) {
        int t = (threadIdx.x >= (unsigned)off) ? tmp[threadIdx.x - off] : 0;
        __syncthreads();
        tmp[threadIdx.x] += t;
        __syncthreads();
    }
    if (i < N) rowp[i] = tmp[threadIdx.x] - v;
    if (threadIdx.x == 255) bsum[blockIdx.x] = tmp[255];
}

__global__ void scan2(int* __restrict__ bsum, int nb) {
    __shared__ int tmp[256];
    int v = (threadIdx.x < (unsigned)nb) ? bsum[threadIdx.x] : 0;
    tmp[threadIdx.x] = v;
    __syncthreads();
    for (int off = 1; off < 256; off <<= 1) {
        int t = (threadIdx.x >= (unsigned)off) ? tmp[threadIdx.x - off] : 0;
        __syncthreads();
        tmp[threadIdx.x] += t;
        __syncthreads();
    }
    if (threadIdx.x < (unsigned)nb) bsum[threadIdx.x] = tmp[threadIdx.x] - v;
}

__global__ void scan3(int* __restrict__ rowp, const int* __restrict__ bsum, int N, int ET) {
    int i = blockIdx.x * 256 + threadIdx.x;
    if (i < N) rowp[i] += bsum[blockIdx.x];
    if (i == 0) rowp[N] = ET;
}

__global__ void scatter_edges(const int* __restrict__ dsts, int E, int ET,
                              const int* __restrict__ rowp, int* __restrict__ cursor,
                              int* __restrict__ eid) {
    int e = blockIdx.x * blockDim.x + threadIdx.x;
    if (e >= ET) return;
    int d = (e < E) ? dsts[e] : (e - E);
    int pos = atomicAdd(&cursor[d], 1);
    eid[rowp[d] + pos] = e;
}

// ---------- GAT layer-2 aggregation: single pass, one wave per dst, H=1 ----------
__global__ __launch_bounds__(256)
void gat_agg1_sp(const int* __restrict__ srcs, int E,
                 const int* __restrict__ rowp, const int* __restrict__ eid,
                 const float* __restrict__ as_, const float* __restrict__ ad_,
                 const float* __restrict__ hfeat, const float* __restrict__ bias,
                 float* __restrict__ g, int N) {
    __shared__ float s_alpha[4][64];
    const int wave = threadIdx.x >> 6;
    const int lane = threadIdx.x & 63;
    const int dst = blockIdx.x * 4 + wave;
    if (dst >= N) return;
    const int start = rowp[dst], end = rowp[dst + 1];
    const float adv = ad_[dst];

    float dsum = 0.0f, acc = 0.0f;
    for (int i0 = start; i0 < end; i0 += 64) {
        int cnt = min(64, end - i0);
        int i = i0 + lane;
        int s = 0;
        if (i < end) {
            int e = eid[i];
            s = (e < E) ? srcs[e] : (e - E);
            float t = as_[s] + adv;
            t = (t > 0.f) ? t : NEG_SLOPE * t;
            float ex = __expf(t);
            dsum += ex;
            s_alpha[wave][lane] = ex;
        }
        __builtin_amdgcn_wave_barrier();
#pragma unroll 4
        for (int k = 0; k < cnt; k++) {
            float a_k = s_alpha[wave][k];
            int   s_k = __shfl(s, k);
            acc += a_k * hfeat[(size_t)s_k * 64 + lane];
        }
        __builtin_amdgcn_wave_barrier();
    }
#pragma unroll
    for (int mk = 32; mk >= 1; mk >>= 1) dsum += __shfl_xor(dsum, mk);
    g[(size_t)dst * 64 + lane] = acc / (dsum + EPS_A) + bias[lane];
}

// ---------- LSTM weight prepack (runs once, 1 block) ----------
__global__ void prep_wsplit(const float* __restrict__ Wih, const float* __restrict__ Whh,
                            const float* __restrict__ bih, const float* __restrict__ bhh,
                            uint32x4* __restrict__ wsp) {
    const int tid = threadIdx.x;          // 0..511
    const int kk = tid >> 7, sub = (tid >> 6) & 1, lane = tid & 63;
    const int grp = lane >> 4, col = lane & 15;
    const int krow = grp * 8;
    const int n = (sub + kk * 2) * 16 + col;
    float w[8];
    *(float4*)&w[0] = *(const float4*)&Whh[n * 32 + krow + 0];
    *(float4*)&w[4] = *(const float4*)&Whh[n * 32 + krow + 4];
    unsigned hi[8], lo[8];
#pragma unroll
    for (int j = 0; j < 8; j++) {
        unsigned short hs = f2bf(w[j]);
        hi[j] = hs;
        lo[j] = f2bf(w[j] - bf2f(hs));
    }
    uint32x4 BH = {hi[0] | (hi[1] << 16), hi[2] | (hi[3] << 16),
                   hi[4] | (hi[5] << 16), hi[6] | (hi[7] << 16)};
    uint32x4 BL = {lo[0] | (lo[1] << 16), lo[2] | (lo[3] << 16),
                   lo[4] | (lo[5] << 16), lo[6] | (lo[7] << 16)};
    float wi0 = Wih[n * 3 + 0], wi1 = Wih[n * 3 + 1], wi2 = Wih[n * 3 + 2];
    float bb = bih[n] + bhh[n];
    unsigned h0 = f2bf(wi0), h1 = f2bf(wi1), h2 = f2bf(wi2), hb = f2bf(bb);
    uint32x4 B2 = {0u, 0u, 0u, 0u};
    if (grp == 0) {
        unsigned bl_ = f2bf(bb - bf2f((unsigned short)hb));
        B2[0] = h0 | (h1 << 16); B2[1] = h2 | (hb << 16);
        B2[2] = h0 | (h1 << 16); B2[3] = h2 | (bl_ << 16);
    } else if (grp == 1) {
        unsigned l0 = f2bf(wi0 - bf2f((unsigned short)h0));
        unsigned l1 = f2bf(wi1 - bf2f((unsigned short)h1));
        unsigned l2 = f2bf(wi2 - bf2f((unsigned short)h2));
        B2[0] = l0 | (l1 << 16); B2[1] = l2;
    }
    wsp[((kk * 3 + 0) * 2 + sub) * 64 + lane] = B2;
    wsp[((kk * 3 + 1) * 2 + sub) * 64 + lane] = BH;
    wsp[((kk * 3 + 2) * 2 + sub) * 64 + lane] = BL;
}

// ---------- FUSED: gat_agg4 || lstm (round-22: r21 race FIXED) ----------
// r21 failed correctness because tt aliased h1+N*128 ("h1 dead after agg")
// -- an invariant the fusion itself broke: lstm blocks wrote tt WHILE agg4
// blocks read the full h1[N][256] gather table. tt now has a DEDICATED
// workspace region; kernel bodies unchanged. lstm (VALU-bound, 1.4% HBM) and
// agg4 (memory-latency gather) are independent; fusing makes wall ~= max
// instead of sum. Interleave 1:8 so lstm blocks spread across CUs.
__global__ __launch_bounds__(256)
void agg4_lstm(const int* __restrict__ srcs, int E,
               const int* __restrict__ rowp, const int* __restrict__ eid,
               const float* __restrict__ as_, const float* __restrict__ ad_,
               const float* __restrict__ hfeat, const float* __restrict__ bias,
               float* __restrict__ g,
               const float* __restrict__ seq, const uint32x4* __restrict__ wsp,
               float* __restrict__ t_out, int N, int nLstm) {
    __shared__ float smem[2304];            // lstm s_h 9.2 KB >= agg4 s_alpha 4 KB

    const int bid = blockIdx.x;
    const bool isLstm = (bid % 9 == 0) && (bid / 9 < nLstm);

    if (isLstm) {
        // ================= LSTM body (r20: pair-split, prepacked frags) =====
        float (*s_h)[2][16][36] = (float(*)[2][16][36])smem;
        const int lbid = bid / 9;
        const int tid  = threadIdx.x;
        const int wave = tid >> 6, lane = tid & 63;
        const int pair = wave >> 1, sub = wave & 1;
        const int grp  = lane >> 4, col = lane & 15;
        const int node0 = lbid * 32 + pair * 16;

#define LF(KK, W) wsp[(((KK) * 3 + (W)) * 2 + sub) * 64 + lane]
        uint32x4 B2_0 = LF(0, 0), BH_0 = LF(0, 1), BL_0 = LF(0, 2);
        uint32x4 B2_1 = LF(1, 0), BH_1 = LF(1, 1), BL_1 = LF(1, 2);
        uint32x4 B2_2 = LF(2, 0), BH_2 = LF(2, 1), BL_2 = LF(2, 2);
        uint32x4 B2_3 = LF(3, 0), BH_3 = LF(3, 1), BL_3 = LF(3, 2);
#undef LF
        asm volatile("" : "+v"(B2_0), "+v"(BH_0), "+v"(BL_0),
                          "+v"(B2_1), "+v"(BH_1), "+v"(BL_1),
                          "+v"(B2_2), "+v"(BH_2), "+v"(BL_2),
                          "+v"(B2_3), "+v"(BH_3), "+v"(BL_3));

        for (int i = tid; i < 2 * 2 * 16 * 36; i += 256) smem[i] = 0.0f;
        __syncthreads();

        float cst0 = 0.f, cst1 = 0.f, cst2 = 0.f, cst3 = 0.f;
        float hn0 = 0.f, hn1 = 0.f, hn2 = 0.f, hn3 = 0.f;
        const floatx4 zac = {0.f, 0.f, 0.f, 0.f};

        const int nodeX = node0 + col;
        const bool vx = (nodeX < N) && (grp < 2);
        const bool g0 = (grp == 0);
        const float* xp = seq + (size_t)nodeX * (T_STEPS * 3);

        float xv0 = vx ? xp[0] : 0.0f;
        float xv1 = vx ? xp[1] : 0.0f;
        float xv2 = vx ? xp[2] : 0.0f;

#pragma unroll 1
        for (int t = 0; t < T_STEPS; t++) {
            unsigned w0 = cvt_pk_bf16(xv0, xv1);
            unsigned w1 = cvt_pk_bf16(xv2, g0 ? 1.0f : 0.0f);
            float e0 = xv0 - lo16f(w0);
            float e1 = xv1 - hi16f(w0);
            float e2 = xv2 - lo16f(w1);
            unsigned w2 = g0 ? cvt_pk_bf16(e0, e1) : 0u;
            unsigned w3 = g0 ? cvt_pk_bf16(e2, 1.0f) : 0u;
            uint32x4 a2p = {w0, w1, w2, w3};
            short8 A2 = bc8(a2p);

            const float* hr = &s_h[pair][(t + 1) & 1][col][grp * 8];
            floatx4 h0 = *(const floatx4*)&hr[0];
            floatx4 h1 = *(const floatx4*)&hr[4];
            unsigned p0 = cvt_pk_bf16(h0[0], h0[1]);
            unsigned p1 = cvt_pk_bf16(h0[2], h0[3]);
            unsigned p2 = cvt_pk_bf16(h1[0], h1[1]);
            unsigned p3 = cvt_pk_bf16(h1[2], h1[3]);
            uint32x4 hip = {p0, p1, p2, p3};
            short8 Ahi = bc8(hip);
            unsigned q0 = cvt_pk_bf16(h0[0] - lo16f(p0), h0[1] - hi16f(p0));
            unsigned q1 = cvt_pk_bf16(h0[2] - lo16f(p1), h0[3] - hi16f(p1));
            unsigned q2 = cvt_pk_bf16(h1[0] - lo16f(p2), h1[1] - hi16f(p2));
            unsigned q3 = cvt_pk_bf16(h1[2] - lo16f(p3), h1[3] - hi16f(p3));
            uint32x4 lop = {q0, q1, q2, q3};
            short8 Alo = bc8(lop);

            {
                int tn = (t + 1 < T_STEPS) ? (t + 1) : t;
                xv0 = vx ? xp[tn * 3 + 0] : 0.0f;
                xv1 = vx ? xp[tn * 3 + 1] : 0.0f;
                xv2 = vx ? xp[tn * 3 + 2] : 0.0f;
            }

            floatx4 d0 = __builtin_amdgcn_mfma_f32_16x16x32_bf16(A2, bc8(B2_0), zac, 0, 0, 0);
            d0 = __builtin_amdgcn_mfma_f32_16x16x32_bf16(Alo, bc8(BH_0), d0, 0, 0, 0);
            d0 = __builtin_amdgcn_mfma_f32_16x16x32_bf16(Ahi, bc8(BL_0), d0, 0, 0, 0);
            d0 = __builtin_amdgcn_mfma_f32_16x16x32_bf16(Ahi, bc8(BH_0), d0, 0, 0, 0);
            floatx4 d1 = __builtin_amdgcn_mfma_f32_16x16x32_bf16(A2, bc8(B2_1), zac, 0, 0, 0);
            d1 = __builtin_amdgcn_mfma_f32_16x16x32_bf16(Alo, bc8(BH_1), d1, 0, 0, 0);
            d1 = __builtin_amdgcn_mfma_f32_16x16x32_bf16(Ahi, bc8(BL_1), d1, 0, 0, 0);
            d1 = __builtin_amdgcn_mfma_f32_16x16x32_bf16(Ahi, bc8(BH_1), d1, 0, 0, 0);
            floatx4 d2 = __builtin_amdgcn_mfma_f32_16x16x32_bf16(A2, bc8(B2_2), zac, 0, 0, 0);
            d2 = __builtin_amdgcn_mfma_f32_16x16x32_bf16(Alo, bc8(BH_2), d2, 0, 0, 0);
            d2 = __builtin_amdgcn_mfma_f32_16x16x32_bf16(Ahi, bc8(BL_2), d2, 0, 0, 0);
            d2 = __builtin_amdgcn_mfma_f32_16x16x32_bf16(Ahi, bc8(BH_2), d2, 0, 0, 0);
            floatx4 d3 = __builtin_amdgcn_mfma_f32_16x16x32_bf16(A2, bc8(B2_3), zac, 0, 0, 0);
            d3 = __builtin_amdgcn_mfma_f32_16x16x32_bf16(Alo, bc8(BH_3), d3, 0, 0, 0);
            d3 = __builtin_amdgcn_mfma_f32_16x16x32_bf16(Ahi, bc8(BL_3), d3, 0, 0, 0);
            d3 = __builtin_amdgcn_mfma_f32_16x16x32_bf16(Ahi, bc8(BH_3), d3, 0, 0, 0);

            {
                float ig, fg, gv, og;
                ig = sigf(d0[0]); fg = sigf(d1[0]); gv = tanhfast(d2[0]); og = sigf(d3[0]);
                cst0 = fg * cst0 + ig * gv; hn0 = og * tanhfast(cst0);
                ig = sigf(d0[1]); fg = sigf(d1[1]); gv = tanhfast(d2[1]); og = sigf(d3[1]);
                cst1 = fg * cst1 + ig * gv; hn1 = og * tanhfast(cst1);
                ig = sigf(d0[2]); fg = sigf(d1[2]); gv = tanhfast(d2[2]); og = sigf(d3[2]);
                cst2 = fg * cst2 + ig * gv; hn2 = og * tanhfast(cst2);
                ig = sigf(d0[3]); fg = sigf(d1[3]); gv = tanhfast(d2[3]); og = sigf(d3[3]);
                cst3 = fg * cst3 + ig * gv; hn3 = og * tanhfast(cst3);
            }

            float* hw = &s_h[pair][t & 1][4 * grp][sub * 16 + col];
            hw[0 * 36] = hn0; hw[1 * 36] = hn1; hw[2 * 36] = hn2; hw[3 * 36] = hn3;
            __syncthreads();
        }

        {
            int node = node0 + 4 * grp;
            const int c = sub * 16 + col;
            if (node + 0 < N) t_out[(size_t)(node + 0) * LSTM_H + c] = hn0;
            if (node + 1 < N) t_out[(size_t)(node + 1) * LSTM_H + c] = hn1;
            if (node + 2 < N) t_out[(size_t)(node + 2) * LSTM_H + c] = hn2;
            if (node + 3 < N) t_out[(size_t)(node + 3) * LSTM_H + c] = hn3;
        }
        return;
    }

    // ================= agg4 body (unchanged; scores O(1) => no segment-max) ==
    {
        float (*s_alpha)[64][4] = (float(*)[64][4])smem;
        const int aid = bid - bid / 9 - 1;      // inverse of interleave map
        const int wave = threadIdx.x >> 6;
        const int lane = threadIdx.x & 63;
        const int head = lane >> 4;
        const int dst = aid * 4 + wave;
        if (dst >= N) return;
        const int start = rowp[dst], end = rowp[dst + 1];
        const float4 adv = ((const float4*)ad_)[dst];
        const float4* h4 = (const float4*)hfeat;

        float4 dsum = make_float4(0.f, 0.f, 0.f, 0.f);
        float4 acc  = make_float4(0.f, 0.f, 0.f, 0.f);

        for (int i0 = start; i0 < end; i0 += 64) {
            int cnt = min(64, end - i0);
            int i = i0 + lane;
            int s = 0;
            if (i < end) {
                int e = eid[i];
                s = (e < E) ? srcs[e] : (e - E);
                float4 a = ((const float4*)as_)[s];
                float tx, ex;
                tx = a.x + adv.x; tx = (tx > 0.f) ? tx : NEG_SLOPE * tx; ex = __expf(tx);
                dsum.x += ex; s_alpha[wave][lane][0] = ex;
                tx = a.y + adv.y; tx = (tx > 0.f) ? tx : NEG_SLOPE * tx; ex = __expf(tx);
                dsum.y += ex; s_alpha[wave][lane][1] = ex;
                tx = a.z + adv.z; tx = (tx > 0.f) ? tx : NEG_SLOPE * tx; ex = __expf(tx);
                dsum.z += ex; s_alpha[wave][lane][2] = ex;
                tx = a.w + adv.w; tx = (tx > 0.f) ? tx : NEG_SLOPE * tx; ex = __expf(tx);
                dsum.w += ex; s_alpha[wave][lane][3] = ex;
            }
            __builtin_amdgcn_wave_barrier();
#pragma unroll 4
            for (int k = 0; k < cnt; k++) {
                float a_k = s_alpha[wave][k][head];
                int   s_k = __shfl(s, k);
                float4 hv = h4[(size_t)s_k * 64 + lane];
                acc.x += a_k * hv.x; acc.y += a_k * hv.y;
                acc.z += a_k * hv.z; acc.w += a_k * hv.w;
            }
            __builtin_amdgcn_wave_barrier();
        }
#pragma unroll
        for (int mk = 32; mk >= 1; mk >>= 1) {
            dsum.x += __shfl_xor(dsum.x, mk);
            dsum.y += __shfl_xor(dsum.y, mk);
            dsum.z += __shfl_xor(dsum.z, mk);
            dsum.w += __shfl_xor(dsum.w, mk);
        }
        float den = (head == 0) ? dsum.x : (head == 1) ? dsum.y : (head == 2) ? dsum.z : dsum.w;
        float inv = 1.0f / (den + EPS_A);
        float4 b4 = ((const float4*)bias)[lane];
        float4 r;
        r.x = acc.x * inv + b4.x; r.x = (r.x > 0.f) ? r.x : __expf(r.x) - 1.f;
        r.y = acc.y * inv + b4.y; r.y = (r.y > 0.f) ? r.y : __expf(r.y) - 1.f;
        r.z = acc.z * inv + b4.z; r.z = (r.z > 0.f) ? r.z : __expf(r.z) - 1.f;
        r.w = acc.w * inv + b4.w; r.w = (r.w > 0.f) ? r.w : __expf(r.w) - 1.f;
        ((float4*)g)[(size_t)dst * 64 + lane] = r;
    }
}

// ---------- fusion MLP ----------
__global__ void fusion_kernel(const float* __restrict__ g2, const float* __restrict__ tt,
                              const float* __restrict__ Wf1, const float* __restrict__ bf1,
                              const float* __restrict__ Wf2, const float* __restrict__ bf2,
                              float* __restrict__ out, int N) {
    __shared__ float sW[96 * 64];
    __shared__ float sb1[64];
    __shared__ float sW2[128];
    for (int i = threadIdx.x; i < 96 * 64; i += 256) sW[i] = Wf1[i];
    if (threadIdx.x < 64) sb1[threadIdx.x] = bf1[threadIdx.x];
    if (threadIdx.x < 128) sW2[threadIdx.x] = Wf2[threadIdx.x];
    __syncthreads();
    const int wave = threadIdx.x >> 6;
    const int lane = threadIdx.x & 63;
    for (int n = blockIdx.x * 4 + wave; n < N; n += gridDim.x * 4) {
        const float* gn = g2 + (size_t)n * 64;
        const float* tn = tt + (size_t)n * 32;
        float acc = sb1[lane];
#pragma unroll 8
        for (int k = 0; k < 64; k++) acc += gn[k] * sW[k * 64 + lane];
#pragma unroll 8
        for (int k = 0; k < 32; k++) acc += tn[k] * sW[(64 + k) * 64 + lane];
        acc = fmaxf(acc, 0.0f);
        float o0 = acc * sW2[lane * 2 + 0];
        float o1 = acc * sW2[lane * 2 + 1];
#pragma unroll
        for (int mk = 32; mk >= 1; mk >>= 1) {
            o0 += __shfl_xor(o0, mk);
            o1 += __shfl_xor(o1, mk);
        }
        if (lane == 0) {
            out[(size_t)n * 2 + 0] = o0 + bf2[0];
            out[(size_t)n * 2 + 1] = o1 + bf2[1];
        }
    }
}

extern "C" void kernel_launch(void* const* d_in, const int* in_sizes, int n_in,
                              void* d_out, int out_size, void* d_ws, size_t ws_size,
                              hipStream_t stream) {
    const float* x      = (const float*)d_in[0];
    const int*   eidx   = (const int*)d_in[1];
    const float* seq    = (const float*)d_in[2];
    const float* W1     = (const float*)d_in[3];
    const float* att_s1 = (const float*)d_in[4];
    const float* att_d1 = (const float*)d_in[5];
    const float* bias1  = (const float*)d_in[6];
    const float* W2     = (const float*)d_in[7];
    const float* att_s2 = (const float*)d_in[8];
    const float* att_d2 = (const float*)d_in[9];
    const float* bias2  = (const float*)d_in[10];
    const float* Wih    = (const float*)d_in[11];
    const float* Whh    = (const float*)d_in[12];
    const float* bih    = (const float*)d_in[13];
    const float* bhh    = (const float*)d_in[14];
    const float* Wf1    = (const float*)d_in[15];
    const float* bf1    = (const float*)d_in[16];
    const float* Wf2    = (const float*)d_in[17];
    const float* bf2    = (const float*)d_in[18];
    float* out = (float*)d_out;

    const int N  = in_sizes[0] / IN_F;   // 50000
    const int E  = in_sizes[1] / 2;      // 800000
    const int ET = E + N;
    const int* srcs = eidx;
    const int* dsts = eidx + E;

    // workspace layout
    float* fws = (float*)d_ws;
    size_t o = 0;
    float* h1  = fws + o; o += (size_t)N * 256;
    float* g1  = fws + o; o += (size_t)N * 256;
    float* tt  = fws + o; o += (size_t)N * 32;   // DEDICATED (r21 race fix:
                                                 // must not alias h1 -- lstm
                                                 // writes it while agg4 reads h1)
    float* as1 = fws + o; o += (size_t)N * 4;
    float* ad1 = fws + o; o += (size_t)N * 4;
    int* cnt    = (int*)(fws + o);
    int* rowp   = cnt + N;
    int* cursor = rowp + N + 1;
    int* eid    = cursor + N;
    int* bsum   = eid + ET;
    // prepacked LSTM weight fragments (24.5 KB, 16B-aligned)
    uintptr_t wp_ = (uintptr_t)(bsum + 512);
    wp_ = (wp_ + 15) & ~(uintptr_t)15;
    uint32x4* wsp = (uint32x4*)wp_;
    // prepacked transposed GEMM weights (hi/lo): W1t 2x32768, W2t 2x16384 shorts
    unsigned short* w1h = (unsigned short*)(wsp + 1536);
    unsigned short* w1l = w1h + 32768;
    unsigned short* w2h = w1l + 32768;
    unsigned short* w2l = w2h + 16384;
    // layer-2 aliases (h1 region dead after the FUSED kernel completes)
    float* h2 = h1;                      // N*64
    float* g2 = h1 + (size_t)N * 64;     // N*64
    float* as2 = as1; float* ad2 = ad1;

    const int nTiles = (N + 255) / 256;
    dim3 blk(256);

    // ---- CSR build ----
    hipMemsetAsync(cnt, 0, (size_t)N * sizeof(int), stream);
    hipMemsetAsync(cursor, 0, (size_t)N * sizeof(int), stream);
    count_deg<<<(ET + 255) / 256, blk, 0, stream>>>(dsts, E, ET, cnt);
    scan1<<<nTiles, blk, 0, stream>>>(cnt, rowp, bsum, N);
    scan2<<<1, blk, 0, stream>>>(bsum, nTiles);
    scan3<<<(N + 256) / 256, blk, 0, stream>>>(rowp, bsum, N, ET);
    scatter_edges<<<(ET + 255) / 256, blk, 0, stream>>>(dsts, E, ET, rowp, cursor, eid);

    // ---- weight prepacks (tiny, once) ----
    prep_wsplit<<<1, 512, 0, stream>>>(Wih, Whh, bih, bhh, wsp);
    prep_wt<128><<<(32768 + 255) / 256, blk, 0, stream>>>(W1, w1h, w1l, 32768, 256);
    prep_wt<256><<<(16384 + 255) / 256, blk, 0, stream>>>(W2, w2h, w2l, 16384, 64);

    // ---- GAT layer 1 GEMM + scores ----
    gemm_mfma<128, 256><<<dim3((N + 127) / 128, 4), blk, 0, stream>>>(x, w1h, w1l, h1, N);
    att_scores<<<(N * 4 + 255) / 256, blk, 0, stream>>>(h1, att_s1, att_d1, as1, ad1, N * 4, 3);

    // ---- FUSED agg4 || lstm (independent workloads, complementary pipes) ----
    {
        const int nLstm = (N + 31) / 32;         // 1563
        const int nAgg  = (N + 3) / 4;           // 12500
        agg4_lstm<<<nLstm + nAgg, blk, 0, stream>>>(srcs, E, rowp, eid, as1, ad1,
                                                    h1, bias1, g1, seq, wsp, tt, N, nLstm);
    }

    // ---- GAT layer 2 ----
    gemm_mfma<256, 64><<<dim3((N + 127) / 128, 1), blk, 0, stream>>>(g1, w2h, w2l, h2, N);
    att_scores<<<(N + 255) / 256, blk, 0, stream>>>(h2, att_s2, att_d2, as2, ad2, N, 0);
    gat_agg1_sp<<<(N + 3) / 4, blk, 0, stream>>>(srcs, E, rowp, eid, as2, ad2, h2, bias2, g2, N);

    // ---- fusion MLP ----
    fusion_kernel<<<512, blk, 0, stream>>>(g2, tt, Wf1, bf1, Wf2, bf2, out, N);
}

// Round 15
// 696.478 us; speedup vs baseline: 1.0586x; 1.0040x over previous
//
#include <hip/hip_runtime.h>
#include <math.h>

#define HEADS1 4
#define HID 64
#define LSTM_H 32
#define IN_F 128
#define T_STEPS 50
#define NEG_SLOPE 0.2f
#define EPS_A 1e-16f

typedef __attribute__((ext_vector_type(8))) short short8;
typedef __attribute__((ext_vector_type(4))) float floatx4;
typedef __attribute__((ext_vector_type(4))) unsigned uint32x4;

// ---------- helpers ----------
__device__ __forceinline__ float frcp(float x) {
    float r;
    asm("v_rcp_f32 %0, %1" : "=v"(r) : "v"(x));
    return r;
}
__device__ __forceinline__ float sigf(float x) { return frcp(1.0f + __expf(-x)); }
__device__ __forceinline__ float tanhfast(float x) {
    float e = __expf(2.0f * x);
    return 1.0f - 2.0f * frcp(e + 1.0f);
}
__device__ __forceinline__ unsigned short f2bf(float f) {
    unsigned u = __float_as_uint(f);
    unsigned r = (u + 0x7FFFu + ((u >> 16) & 1u)) >> 16;
    return (unsigned short)r;
}
__device__ __forceinline__ float bf2f(unsigned short s) {
    return __uint_as_float(((unsigned)s) << 16);
}
__device__ __forceinline__ unsigned cvt_pk_bf16(float a, float b) {
    unsigned r;
    asm("v_cvt_pk_bf16_f32 %0, %1, %2" : "=v"(r) : "v"(a), "v"(b));
    return r;
}
__device__ __forceinline__ float lo16f(unsigned p) { return __uint_as_float(p << 16); }
__device__ __forceinline__ float hi16f(unsigned p) { return __uint_as_float(p & 0xffff0000u); }
__device__ __forceinline__ short8 bc8(uint32x4 v) { return __builtin_bit_cast(short8, v); }

// ---------- weight transpose+split prepack for MFMA GEMM ----------
template <int KK>
__global__ void prep_wt(const float* __restrict__ W, unsigned short* __restrict__ th,
                        unsigned short* __restrict__ tl, int total, int NC) {
    int i = blockIdx.x * 256 + threadIdx.x;
    if (i >= total) return;
    int n = i / KK, k = i - n * KK;
    float v = W[k * NC + n];
    unsigned short h = f2bf(v);
    th[i] = h;
    tl[i] = f2bf(v - bf2f(h));
}

// ---------- MFMA GEMM: C[M,NC] = A[M,K] @ B[K,NC], split-bf16 3-product ----
template <int K, int NC>
__global__ __launch_bounds__(256)
void gemm_mfma(const float* __restrict__ A, const unsigned short* __restrict__ Bth,
               const unsigned short* __restrict__ Btl, float* __restrict__ C, int M) {
    __shared__ float sA[128][44];
    __shared__ unsigned short sBh[64][40];
    __shared__ unsigned short sBl[64][40];
    const int tid = threadIdx.x;
    const int wave = tid >> 6, lane = tid & 63;
    const int wr = wave >> 1, wc = wave & 1;
    const int row0 = blockIdx.x * 128;
    const int col0 = blockIdx.y * 64;
    const int l15 = lane & 15, l4 = lane >> 4;

    floatx4 acc[4][2];
#pragma unroll
    for (int rb = 0; rb < 4; rb++)
#pragma unroll
        for (int cb = 0; cb < 2; cb++) acc[rb][cb] = (floatx4){0.f, 0.f, 0.f, 0.f};

    for (int k0 = 0; k0 < K; k0 += 32) {
        __syncthreads();
#pragma unroll
        for (int q = 0; q < 4; q++) {
            int idx = q * 256 + tid;
            int row = idx >> 3, seg = idx & 7;
            int gr = row0 + row;
            float4 v = (gr < M) ? *(const float4*)&A[(size_t)gr * K + k0 + seg * 4]
                                : make_float4(0.f, 0.f, 0.f, 0.f);
            *(float4*)&sA[row][seg * 4] = v;
        }
        {
            int col = tid >> 2, seg = tid & 3;
            size_t gb = (size_t)(col0 + col) * K + k0 + seg * 8;
            *(short8*)&sBh[col][seg * 8] = *(const short8*)&Bth[gb];
            *(short8*)&sBl[col][seg * 8] = *(const short8*)&Btl[gb];
        }
        __syncthreads();

        short8 bh0 = *(const short8*)&sBh[wc * 32 + 0 + l15][l4 * 8];
        short8 bl0 = *(const short8*)&sBl[wc * 32 + 0 + l15][l4 * 8];
        short8 bh1 = *(const short8*)&sBh[wc * 32 + 16 + l15][l4 * 8];
        short8 bl1 = *(const short8*)&sBl[wc * 32 + 16 + l15][l4 * 8];

#pragma unroll
        for (int rb = 0; rb < 4; rb++) {
            int row = wr * 64 + rb * 16 + l15;
            floatx4 a0 = *(const floatx4*)&sA[row][l4 * 8 + 0];
            floatx4 a1 = *(const floatx4*)&sA[row][l4 * 8 + 4];
            unsigned p0 = cvt_pk_bf16(a0[0], a0[1]);
            unsigned p1 = cvt_pk_bf16(a0[2], a0[3]);
            unsigned p2 = cvt_pk_bf16(a1[0], a1[1]);
            unsigned p3 = cvt_pk_bf16(a1[2], a1[3]);
            uint32x4 hp = {p0, p1, p2, p3};
            short8 Ah = bc8(hp);
            unsigned q0 = cvt_pk_bf16(a0[0] - lo16f(p0), a0[1] - hi16f(p0));
            unsigned q1 = cvt_pk_bf16(a0[2] - lo16f(p1), a0[3] - hi16f(p1));
            unsigned q2 = cvt_pk_bf16(a1[0] - lo16f(p2), a1[1] - hi16f(p2));
            unsigned q3 = cvt_pk_bf16(a1[2] - lo16f(p3), a1[3] - hi16f(p3));
            uint32x4 lp = {q0, q1, q2, q3};
            short8 Al = bc8(lp);

            acc[rb][0] = __builtin_amdgcn_mfma_f32_16x16x32_bf16(Ah, bh0, acc[rb][0], 0, 0, 0);
            acc[rb][0] = __builtin_amdgcn_mfma_f32_16x16x32_bf16(Ah, bl0, acc[rb][0], 0, 0, 0);
            acc[rb][0] = __builtin_amdgcn_mfma_f32_16x16x32_bf16(Al, bh0, acc[rb][0], 0, 0, 0);
            acc[rb][1] = __builtin_amdgcn_mfma_f32_16x16x32_bf16(Ah, bh1, acc[rb][1], 0, 0, 0);
            acc[rb][1] = __builtin_amdgcn_mfma_f32_16x16x32_bf16(Ah, bl1, acc[rb][1], 0, 0, 0);
            acc[rb][1] = __builtin_amdgcn_mfma_f32_16x16x32_bf16(Al, bh1, acc[rb][1], 0, 0, 0);
        }
    }

#pragma unroll
    for (int rb = 0; rb < 4; rb++)
#pragma unroll
        for (int cb = 0; cb < 2; cb++)
#pragma unroll
            for (int q = 0; q < 4; q++) {
                int row = row0 + wr * 64 + rb * 16 + l4 * 4 + q;
                int col = col0 + wc * 32 + cb * 16 + l15;
                if (row < M) C[(size_t)row * NC + col] = acc[rb][cb][q];
            }
}

// ---------- FUSED: gemm1 || count_deg (round-23; independent workloads) ----
// gemm1 (MFMA/LDS-bound) reads x/W1; count_deg (random-atomic) reads edges.
// No data dependence -> horizontal fusion removes their serialization.
__global__ __launch_bounds__(256)
void gemm1_count(const float* __restrict__ A, const unsigned short* __restrict__ Bth,
                 const unsigned short* __restrict__ Btl, float* __restrict__ C, int M,
                 const int* __restrict__ dsts, int E, int ET, int* __restrict__ cnt,
                 int nGemmRow) {
    __shared__ float sA[128][44];
    __shared__ unsigned short sBh[64][40];
    __shared__ unsigned short sBl[64][40];
    const int bid = blockIdx.x;
    const int nGemm = nGemmRow * 4;

    if (bid >= nGemm) {
        int e = (bid - nGemm) * 256 + threadIdx.x;
        if (e < ET) {
            int d = (e < E) ? dsts[e] : (e - E);
            atomicAdd(&cnt[d], 1);
        }
        return;
    }

    constexpr int K = 128, NC = 256;
    const int tid = threadIdx.x;
    const int wave = tid >> 6, lane = tid & 63;
    const int wr = wave >> 1, wc = wave & 1;
    const int row0 = (bid / 4) * 128;
    const int col0 = (bid & 3) * 64;
    const int l15 = lane & 15, l4 = lane >> 4;

    floatx4 acc[4][2];
#pragma unroll
    for (int rb = 0; rb < 4; rb++)
#pragma unroll
        for (int cb = 0; cb < 2; cb++) acc[rb][cb] = (floatx4){0.f, 0.f, 0.f, 0.f};

    for (int k0 = 0; k0 < K; k0 += 32) {
        __syncthreads();
#pragma unroll
        for (int q = 0; q < 4; q++) {
            int idx = q * 256 + tid;
            int row = idx >> 3, seg = idx & 7;
            int gr = row0 + row;
            float4 v = (gr < M) ? *(const float4*)&A[(size_t)gr * K + k0 + seg * 4]
                                : make_float4(0.f, 0.f, 0.f, 0.f);
            *(float4*)&sA[row][seg * 4] = v;
        }
        {
            int col = tid >> 2, seg = tid & 3;
            size_t gb = (size_t)(col0 + col) * K + k0 + seg * 8;
            *(short8*)&sBh[col][seg * 8] = *(const short8*)&Bth[gb];
            *(short8*)&sBl[col][seg * 8] = *(const short8*)&Btl[gb];
        }
        __syncthreads();

        short8 bh0 = *(const short8*)&sBh[wc * 32 + 0 + l15][l4 * 8];
        short8 bl0 = *(const short8*)&sBl[wc * 32 + 0 + l15][l4 * 8];
        short8 bh1 = *(const short8*)&sBh[wc * 32 + 16 + l15][l4 * 8];
        short8 bl1 = *(const short8*)&sBl[wc * 32 + 16 + l15][l4 * 8];

#pragma unroll
        for (int rb = 0; rb < 4; rb++) {
            int row = wr * 64 + rb * 16 + l15;
            floatx4 a0 = *(const floatx4*)&sA[row][l4 * 8 + 0];
            floatx4 a1 = *(const floatx4*)&sA[row][l4 * 8 + 4];
            unsigned p0 = cvt_pk_bf16(a0[0], a0[1]);
            unsigned p1 = cvt_pk_bf16(a0[2], a0[3]);
            unsigned p2 = cvt_pk_bf16(a1[0], a1[1]);
            unsigned p3 = cvt_pk_bf16(a1[2], a1[3]);
            uint32x4 hp = {p0, p1, p2, p3};
            short8 Ah = bc8(hp);
            unsigned q0 = cvt_pk_bf16(a0[0] - lo16f(p0), a0[1] - hi16f(p0));
            unsigned q1 = cvt_pk_bf16(a0[2] - lo16f(p1), a0[3] - hi16f(p1));
            unsigned q2 = cvt_pk_bf16(a1[0] - lo16f(p2), a1[1] - hi16f(p2));
            unsigned q3 = cvt_pk_bf16(a1[2] - lo16f(p3), a1[3] - hi16f(p3));
            uint32x4 lp = {q0, q1, q2, q3};
            short8 Al = bc8(lp);

            acc[rb][0] = __builtin_amdgcn_mfma_f32_16x16x32_bf16(Ah, bh0, acc[rb][0], 0, 0, 0);
            acc[rb][0] = __builtin_amdgcn_mfma_f32_16x16x32_bf16(Ah, bl0, acc[rb][0], 0, 0, 0);
            acc[rb][0] = __builtin_amdgcn_mfma_f32_16x16x32_bf16(Al, bh0, acc[rb][0], 0, 0, 0);
            acc[rb][1] = __builtin_amdgcn_mfma_f32_16x16x32_bf16(Ah, bh1, acc[rb][1], 0, 0, 0);
            acc[rb][1] = __builtin_amdgcn_mfma_f32_16x16x32_bf16(Ah, bl1, acc[rb][1], 0, 0, 0);
            acc[rb][1] = __builtin_amdgcn_mfma_f32_16x16x32_bf16(Al, bh1, acc[rb][1], 0, 0, 0);
        }
    }

#pragma unroll
    for (int rb = 0; rb < 4; rb++)
#pragma unroll
        for (int cb = 0; cb < 2; cb++)
#pragma unroll
            for (int q = 0; q < 4; q++) {
                int row = row0 + wr * 64 + rb * 16 + l4 * 4 + q;
                int col = col0 + wc * 32 + cb * 16 + l15;
                if (row < M) C[(size_t)row * 256 + col] = acc[rb][cb][q];
            }
}

// ---------- FUSED: att_scores1 || scatter_edges (round-23) ----------
// scores1 needs h1 (ready); scatter needs rowp (ready). Independent.
__global__ void sc1_scatter(const float* __restrict__ h, const float* __restrict__ att_s,
                            const float* __restrict__ att_d, float* __restrict__ as_,
                            float* __restrict__ ad_, int NH,
                            const int* __restrict__ dsts, int E, int ET,
                            const int* __restrict__ rowp, int* __restrict__ cursor,
                            int* __restrict__ eid, int nScore) {
    const int bid = blockIdx.x;
    if (bid >= nScore) {
        int e = (bid - nScore) * 256 + threadIdx.x;
        if (e < ET) {
            int d = (e < E) ? dsts[e] : (e - E);
            int pos = atomicAdd(&cursor[d], 1);
            eid[rowp[d] + pos] = e;
        }
        return;
    }
    int i = bid * 256 + threadIdx.x;
    if (i >= NH) return;
    int hh = i & 3;
    const float* row = h + (size_t)i * HID;
    float s = 0.0f, d = 0.0f;
#pragma unroll 8
    for (int c = 0; c < HID; c++) {
        float v = row[c];
        s += v * att_s[hh * HID + c];
        d += v * att_d[hh * HID + c];
    }
    as_[i] = s;
    ad_[i] = d;
}

// ---------- attention scores (layer 2, standalone) ----------
__global__ void att_scores(const float* __restrict__ h, const float* __restrict__ att_s,
                           const float* __restrict__ att_d, float* __restrict__ as_,
                           float* __restrict__ ad_, int NH, int Hmask) {
    int i = blockIdx.x * blockDim.x + threadIdx.x;
    if (i >= NH) return;
    int hh = i & Hmask;
    const float* row = h + (size_t)i * HID;
    float s = 0.0f, d = 0.0f;
#pragma unroll 8
    for (int c = 0; c < HID; c++) {
        float v = row[c];
        s += v * att_s[hh * HID + c];
        d += v * att_d[hh * HID + c];
    }
    as_[i] = s;
    ad_[i] = d;
}

// ---------- CSR scans ----------
__global__ void scan1(const int* __restrict__ cnt, int* __restrict__ rowp,
                      int* __restrict__ bsum, int N) {
    __shared__ int tmp[256];
    int i = blockIdx.x * 256 + threadIdx.x;
    int v = (i < N) ? cnt[i] : 0;
    tmp[threadIdx.x] = v;
    __syncthreads();
    for (int off = 1; off < 256; off <<= 1) {
        int t = (threadIdx.x >= (unsigned)off) ? tmp[threadIdx.x - off] : 0;
        __syncthreads();
        tmp[threadIdx.x] += t;
        __syncthreads();
    }
    if (i < N) rowp[i] = tmp[threadIdx.x] - v;
    if (threadIdx.x == 255) bsum[blockIdx.x] = tmp[255];
}

__global__ void scan2(int* __restrict__ bsum, int nb) {
    __shared__ int tmp[256];
    int v = (threadIdx.x < (unsigned)nb) ? bsum[threadIdx.x] : 0;
    tmp[threadIdx.x] = v;
    __syncthreads();
    for (int off = 1; off < 256; off <<= 1) {
        int t = (threadIdx.x >= (unsigned)off) ? tmp[threadIdx.x - off] : 0;
        __syncthreads();
        tmp[threadIdx.x] += t;
        __syncthreads();
    }
    if (threadIdx.x < (unsigned)nb) bsum[threadIdx.x] = tmp[threadIdx.x] - v;
}

__global__ void scan3(int* __restrict__ rowp, const int* __restrict__ bsum, int N, int ET) {
    int i = blockIdx.x * 256 + threadIdx.x;
    if (i < N) rowp[i] += bsum[blockIdx.x];
    if (i == 0) rowp[N] = ET;
}

// ---------- LSTM weight prepack (runs once, 1 block) ----------
__global__ void prep_wsplit(const float* __restrict__ Wih, const float* __restrict__ Whh,
                            const float* __restrict__ bih, const float* __restrict__ bhh,
                            uint32x4* __restrict__ wsp) {
    const int tid = threadIdx.x;          // 0..511
    const int kk = tid >> 7, sub = (tid >> 6) & 1, lane = tid & 63;
    const int grp = lane >> 4, col = lane & 15;
    const int krow = grp * 8;
    const int n = (sub + kk * 2) * 16 + col;
    float w[8];
    *(float4*)&w[0] = *(const float4*)&Whh[n * 32 + krow + 0];
    *(float4*)&w[4] = *(const float4*)&Whh[n * 32 + krow + 4];
    unsigned hi[8], lo[8];
#pragma unroll
    for (int j = 0; j < 8; j++) {
        unsigned short hs = f2bf(w[j]);
        hi[j] = hs;
        lo[j] = f2bf(w[j] - bf2f(hs));
    }
    uint32x4 BH = {hi[0] | (hi[1] << 16), hi[2] | (hi[3] << 16),
                   hi[4] | (hi[5] << 16), hi[6] | (hi[7] << 16)};
    uint32x4 BL = {lo[0] | (lo[1] << 16), lo[2] | (lo[3] << 16),
                   lo[4] | (lo[5] << 16), lo[6] | (lo[7] << 16)};
    float wi0 = Wih[n * 3 + 0], wi1 = Wih[n * 3 + 1], wi2 = Wih[n * 3 + 2];
    float bb = bih[n] + bhh[n];
    unsigned h0 = f2bf(wi0), h1 = f2bf(wi1), h2 = f2bf(wi2), hb = f2bf(bb);
    uint32x4 B2 = {0u, 0u, 0u, 0u};
    if (grp == 0) {
        unsigned bl_ = f2bf(bb - bf2f((unsigned short)hb));
        B2[0] = h0 | (h1 << 16); B2[1] = h2 | (hb << 16);
        B2[2] = h0 | (h1 << 16); B2[3] = h2 | (bl_ << 16);
    } else if (grp == 1) {
        unsigned l0 = f2bf(wi0 - bf2f((unsigned short)h0));
        unsigned l1 = f2bf(wi1 - bf2f((unsigned short)h1));
        unsigned l2 = f2bf(wi2 - bf2f((unsigned short)h2));
        B2[0] = l0 | (l1 << 16); B2[1] = l2;
    }
    wsp[((kk * 3 + 0) * 2 + sub) * 64 + lane] = B2;
    wsp[((kk * 3 + 1) * 2 + sub) * 64 + lane] = BH;
    wsp[((kk * 3 + 2) * 2 + sub) * 64 + lane] = BL;
}

// ---------- FUSED: gat_agg4 || lstm (r22, unchanged) ----------
__global__ __launch_bounds__(256)
void agg4_lstm(const int* __restrict__ srcs, int E,
               const int* __restrict__ rowp, const int* __restrict__ eid,
               const float* __restrict__ as_, const float* __restrict__ ad_,
               const float* __restrict__ hfeat, const float* __restrict__ bias,
               float* __restrict__ g,
               const float* __restrict__ seq, const uint32x4* __restrict__ wsp,
               float* __restrict__ t_out, int N, int nLstm) {
    __shared__ float smem[2304];

    const int bid = blockIdx.x;
    const bool isLstm = (bid % 9 == 0) && (bid / 9 < nLstm);

    if (isLstm) {
        float (*s_h)[2][16][36] = (float(*)[2][16][36])smem;
        const int lbid = bid / 9;
        const int tid  = threadIdx.x;
        const int wave = tid >> 6, lane = tid & 63;
        const int pair = wave >> 1, sub = wave & 1;
        const int grp  = lane >> 4, col = lane & 15;
        const int node0 = lbid * 32 + pair * 16;

#define LF(KK, W) wsp[(((KK) * 3 + (W)) * 2 + sub) * 64 + lane]
        uint32x4 B2_0 = LF(0, 0), BH_0 = LF(0, 1), BL_0 = LF(0, 2);
        uint32x4 B2_1 = LF(1, 0), BH_1 = LF(1, 1), BL_1 = LF(1, 2);
        uint32x4 B2_2 = LF(2, 0), BH_2 = LF(2, 1), BL_2 = LF(2, 2);
        uint32x4 B2_3 = LF(3, 0), BH_3 = LF(3, 1), BL_3 = LF(3, 2);
#undef LF
        asm volatile("" : "+v"(B2_0), "+v"(BH_0), "+v"(BL_0),
                          "+v"(B2_1), "+v"(BH_1), "+v"(BL_1),
                          "+v"(B2_2), "+v"(BH_2), "+v"(BL_2),
                          "+v"(B2_3), "+v"(BH_3), "+v"(BL_3));

        for (int i = tid; i < 2 * 2 * 16 * 36; i += 256) smem[i] = 0.0f;
        __syncthreads();

        float cst0 = 0.f, cst1 = 0.f, cst2 = 0.f, cst3 = 0.f;
        float hn0 = 0.f, hn1 = 0.f, hn2 = 0.f, hn3 = 0.f;
        const floatx4 zac = {0.f, 0.f, 0.f, 0.f};

        const int nodeX = node0 + col;
        const bool vx = (nodeX < N) && (grp < 2);
        const bool g0 = (grp == 0);
        const float* xp = seq + (size_t)nodeX * (T_STEPS * 3);

        float xv0 = vx ? xp[0] : 0.0f;
        float xv1 = vx ? xp[1] : 0.0f;
        float xv2 = vx ? xp[2] : 0.0f;

#pragma unroll 1
        for (int t = 0; t < T_STEPS; t++) {
            unsigned w0 = cvt_pk_bf16(xv0, xv1);
            unsigned w1 = cvt_pk_bf16(xv2, g0 ? 1.0f : 0.0f);
            float e0 = xv0 - lo16f(w0);
            float e1 = xv1 - hi16f(w0);
            float e2 = xv2 - lo16f(w1);
            unsigned w2 = g0 ? cvt_pk_bf16(e0, e1) : 0u;
            unsigned w3 = g0 ? cvt_pk_bf16(e2, 1.0f) : 0u;
            uint32x4 a2p = {w0, w1, w2, w3};
            short8 A2 = bc8(a2p);

            const float* hr = &s_h[pair][(t + 1) & 1][col][grp * 8];
            floatx4 h0 = *(const floatx4*)&hr[0];
            floatx4 h1 = *(const floatx4*)&hr[4];
            unsigned p0 = cvt_pk_bf16(h0[0], h0[1]);
            unsigned p1 = cvt_pk_bf16(h0[2], h0[3]);
            unsigned p2 = cvt_pk_bf16(h1[0], h1[1]);
            unsigned p3 = cvt_pk_bf16(h1[2], h1[3]);
            uint32x4 hip = {p0, p1, p2, p3};
            short8 Ahi = bc8(hip);
            unsigned q0 = cvt_pk_bf16(h0[0] - lo16f(p0), h0[1] - hi16f(p0));
            unsigned q1 = cvt_pk_bf16(h0[2] - lo16f(p1), h0[3] - hi16f(p1));
            unsigned q2 = cvt_pk_bf16(h1[0] - lo16f(p2), h1[1] - hi16f(p2));
            unsigned q3 = cvt_pk_bf16(h1[2] - lo16f(p3), h1[3] - hi16f(p3));
            uint32x4 lop = {q0, q1, q2, q3};
            short8 Alo = bc8(lop);

            {
                int tn = (t + 1 < T_STEPS) ? (t + 1) : t;
                xv0 = vx ? xp[tn * 3 + 0] : 0.0f;
                xv1 = vx ? xp[tn * 3 + 1] : 0.0f;
                xv2 = vx ? xp[tn * 3 + 2] : 0.0f;
            }

            floatx4 d0 = __builtin_amdgcn_mfma_f32_16x16x32_bf16(A2, bc8(B2_0), zac, 0, 0, 0);
            d0 = __builtin_amdgcn_mfma_f32_16x16x32_bf16(Alo, bc8(BH_0), d0, 0, 0, 0);
            d0 = __builtin_amdgcn_mfma_f32_16x16x32_bf16(Ahi, bc8(BL_0), d0, 0, 0, 0);
            d0 = __builtin_amdgcn_mfma_f32_16x16x32_bf16(Ahi, bc8(BH_0), d0, 0, 0, 0);
            floatx4 d1 = __builtin_amdgcn_mfma_f32_16x16x32_bf16(A2, bc8(B2_1), zac, 0, 0, 0);
            d1 = __builtin_amdgcn_mfma_f32_16x16x32_bf16(Alo, bc8(BH_1), d1, 0, 0, 0);
            d1 = __builtin_amdgcn_mfma_f32_16x16x32_bf16(Ahi, bc8(BL_1), d1, 0, 0, 0);
            d1 = __builtin_amdgcn_mfma_f32_16x16x32_bf16(Ahi, bc8(BH_1), d1, 0, 0, 0);
            floatx4 d2 = __builtin_amdgcn_mfma_f32_16x16x32_bf16(A2, bc8(B2_2), zac, 0, 0, 0);
            d2 = __builtin_amdgcn_mfma_f32_16x16x32_bf16(Alo, bc8(BH_2), d2, 0, 0, 0);
            d2 = __builtin_amdgcn_mfma_f32_16x16x32_bf16(Ahi, bc8(BL_2), d2, 0, 0, 0);
            d2 = __builtin_amdgcn_mfma_f32_16x16x32_bf16(Ahi, bc8(BH_2), d2, 0, 0, 0);
            floatx4 d3 = __builtin_amdgcn_mfma_f32_16x16x32_bf16(A2, bc8(B2_3), zac, 0, 0, 0);
            d3 = __builtin_amdgcn_mfma_f32_16x16x32_bf16(Alo, bc8(BH_3), d3, 0, 0, 0);
            d3 = __builtin_amdgcn_mfma_f32_16x16x32_bf16(Ahi, bc8(BL_3), d3, 0, 0, 0);
            d3 = __builtin_amdgcn_mfma_f32_16x16x32_bf16(Ahi, bc8(BH_3), d3, 0, 0, 0);

            {
                float ig, fg, gv, og;
                ig = sigf(d0[0]); fg = sigf(d1[0]); gv = tanhfast(d2[0]); og = sigf(d3[0]);
                cst0 = fg * cst0 + ig * gv; hn0 = og * tanhfast(cst0);
                ig = sigf(d0[1]); fg = sigf(d1[1]); gv = tanhfast(d2[1]); og = sigf(d3[1]);
                cst1 = fg * cst1 + ig * gv; hn1 = og * tanhfast(cst1);
                ig = sigf(d0[2]); fg = sigf(d1[2]); gv = tanhfast(d2[2]); og = sigf(d3[2]);
                cst2 = fg * cst2 + ig * gv; hn2 = og * tanhfast(cst2);
                ig = sigf(d0[3]); fg = sigf(d1[3]); gv = tanhfast(d2[3]); og = sigf(d3[3]);
                cst3 = fg * cst3 + ig * gv; hn3 = og * tanhfast(cst3);
            }

            float* hw = &s_h[pair][t & 1][4 * grp][sub * 16 + col];
            hw[0 * 36] = hn0; hw[1 * 36] = hn1; hw[2 * 36] = hn2; hw[3 * 36] = hn3;
            __syncthreads();
        }

        {
            int node = node0 + 4 * grp;
            const int c = sub * 16 + col;
            if (node + 0 < N) t_out[(size_t)(node + 0) * LSTM_H + c] = hn0;
            if (node + 1 < N) t_out[(size_t)(node + 1) * LSTM_H + c] = hn1;
            if (node + 2 < N) t_out[(size_t)(node + 2) * LSTM_H + c] = hn2;
            if (node + 3 < N) t_out[(size_t)(node + 3) * LSTM_H + c] = hn3;
        }
        return;
    }

    {
        float (*s_alpha)[64][4] = (float(*)[64][4])smem;
        const int aid = bid - bid / 9 - 1;
        const int wave = threadIdx.x >> 6;
        const int lane = threadIdx.x & 63;
        const int head = lane >> 4;
        const int dst = aid * 4 + wave;
        if (dst >= N) return;
        const int start = rowp[dst], end = rowp[dst + 1];
        const float4 adv = ((const float4*)ad_)[dst];
        const float4* h4 = (const float4*)hfeat;

        float4 dsum = make_float4(0.f, 0.f, 0.f, 0.f);
        float4 acc  = make_float4(0.f, 0.f, 0.f, 0.f);

        for (int i0 = start; i0 < end; i0 += 64) {
            int cnt = min(64, end - i0);
            int i = i0 + lane;
            int s = 0;
            if (i < end) {
                int e = eid[i];
                s = (e < E) ? srcs[e] : (e - E);
                float4 a = ((const float4*)as_)[s];
                float tx, ex;
                tx = a.x + adv.x; tx = (tx > 0.f) ? tx : NEG_SLOPE * tx; ex = __expf(tx);
                dsum.x += ex; s_alpha[wave][lane][0] = ex;
                tx = a.y + adv.y; tx = (tx > 0.f) ? tx : NEG_SLOPE * tx; ex = __expf(tx);
                dsum.y += ex; s_alpha[wave][lane][1] = ex;
                tx = a.z + adv.z; tx = (tx > 0.f) ? tx : NEG_SLOPE * tx; ex = __expf(tx);
                dsum.z += ex; s_alpha[wave][lane][2] = ex;
                tx = a.w + adv.w; tx = (tx > 0.f) ? tx : NEG_SLOPE * tx; ex = __expf(tx);
                dsum.w += ex; s_alpha[wave][lane][3] = ex;
            }
            __builtin_amdgcn_wave_barrier();
#pragma unroll 4
            for (int k = 0; k < cnt; k++) {
                float a_k = s_alpha[wave][k][head];
                int   s_k = __shfl(s, k);
                float4 hv = h4[(size_t)s_k * 64 + lane];
                acc.x += a_k * hv.x; acc.y += a_k * hv.y;
                acc.z += a_k * hv.z; acc.w += a_k * hv.w;
            }
            __builtin_amdgcn_wave_barrier();
        }
#pragma unroll
        for (int mk = 32; mk >= 1; mk >>= 1) {
            dsum.x += __shfl_xor(dsum.x, mk);
            dsum.y += __shfl_xor(dsum.y, mk);
            dsum.z += __shfl_xor(dsum.z, mk);
            dsum.w += __shfl_xor(dsum.w, mk);
        }
        float den = (head == 0) ? dsum.x : (head == 1) ? dsum.y : (head == 2) ? dsum.z : dsum.w;
        float inv = 1.0f / (den + EPS_A);
        float4 b4 = ((const float4*)bias)[lane];
        float4 r;
        r.x = acc.x * inv + b4.x; r.x = (r.x > 0.f) ? r.x : __expf(r.x) - 1.f;
        r.y = acc.y * inv + b4.y; r.y = (r.y > 0.f) ? r.y : __expf(r.y) - 1.f;
        r.z = acc.z * inv + b4.z; r.z = (r.z > 0.f) ? r.z : __expf(r.z) - 1.f;
        r.w = acc.w * inv + b4.w; r.w = (r.w > 0.f) ? r.w : __expf(r.w) - 1.f;
        ((float4*)g)[(size_t)dst * 64 + lane] = r;
    }
}

// ---------- FUSED: gat_agg1 + fusion MLP (round-23 vertical fusion) ----------
// agg1's wave holds the g2 row in registers (one channel/lane). Apply the MLP
// directly via 96 shfl+FMA against LDS-staged Wf1 and write out -- kills the
// g2 global roundtrip (25 MB) and a kernel launch. Math order identical to
// the old fusion_kernel (same k loop order, same values).
__global__ __launch_bounds__(256)
void agg1_mlp(const int* __restrict__ srcs, int E,
              const int* __restrict__ rowp, const int* __restrict__ eid,
              const float* __restrict__ as_, const float* __restrict__ ad_,
              const float* __restrict__ hfeat, const float* __restrict__ bias,
              const float* __restrict__ tt,
              const float* __restrict__ Wf1, const float* __restrict__ bf1,
              const float* __restrict__ Wf2, const float* __restrict__ bf2,
              float* __restrict__ out, int N) {
    __shared__ float s_alpha[4][64];
    __shared__ float sW[96 * 64];
    __shared__ float sb1[64];
    __shared__ float sW2[128];
    for (int i = threadIdx.x; i < 96 * 64; i += 256) sW[i] = Wf1[i];
    if (threadIdx.x < 64) sb1[threadIdx.x] = bf1[threadIdx.x];
    if (threadIdx.x < 128) sW2[threadIdx.x] = Wf2[threadIdx.x];
    __syncthreads();

    const int wave = threadIdx.x >> 6;
    const int lane = threadIdx.x & 63;
    const int dst = blockIdx.x * 4 + wave;
    if (dst >= N) return;
    const int start = rowp[dst], end = rowp[dst + 1];
    const float adv = ad_[dst];

    float dsum = 0.0f, acc = 0.0f;
    for (int i0 = start; i0 < end; i0 += 64) {
        int cnt = min(64, end - i0);
        int i = i0 + lane;
        int s = 0;
        if (i < end) {
            int e = eid[i];
            s = (e < E) ? srcs[e] : (e - E);
            float t = as_[s] + adv;
            t = (t > 0.f) ? t : NEG_SLOPE * t;
            float ex = __expf(t);
            dsum += ex;
            s_alpha[wave][lane] = ex;
        }
        __builtin_amdgcn_wave_barrier();
#pragma unroll 4
        for (int k = 0; k < cnt; k++) {
            float a_k = s_alpha[wave][k];
            int   s_k = __shfl(s, k);
            acc += a_k * hfeat[(size_t)s_k * 64 + lane];
        }
        __builtin_amdgcn_wave_barrier();
    }
#pragma unroll
    for (int mk = 32; mk >= 1; mk >>= 1) dsum += __shfl_xor(dsum, mk);
    const float gval = acc / (dsum + EPS_A) + bias[lane];   // g2[dst*64+lane]

    // ---- MLP (same order as old fusion_kernel) ----
    float tval = (lane < 32) ? tt[(size_t)dst * 32 + lane] : 0.0f;
    float m = sb1[lane];
#pragma unroll 8
    for (int k = 0; k < 64; k++) m += __shfl(gval, k) * sW[k * 64 + lane];
#pragma unroll 8
    for (int k = 0; k < 32; k++) m += __shfl(tval, k) * sW[(64 + k) * 64 + lane];
    m = fmaxf(m, 0.0f);
    float o0 = m * sW2[lane * 2 + 0];
    float o1 = m * sW2[lane * 2 + 1];
#pragma unroll
    for (int mk = 32; mk >= 1; mk >>= 1) {
        o0 += __shfl_xor(o0, mk);
        o1 += __shfl_xor(o1, mk);
    }
    if (lane == 0) {
        out[(size_t)dst * 2 + 0] = o0 + bf2[0];
        out[(size_t)dst * 2 + 1] = o1 + bf2[1];
    }
}

extern "C" void kernel_launch(void* const* d_in, const int* in_sizes, int n_in,
                              void* d_out, int out_size, void* d_ws, size_t ws_size,
                              hipStream_t stream) {
    const float* x      = (const float*)d_in[0];
    const int*   eidx   = (const int*)d_in[1];
    const float* seq    = (const float*)d_in[2];
    const float* W1     = (const float*)d_in[3];
    const float* att_s1 = (const float*)d_in[4];
    const float* att_d1 = (const float*)d_in[5];
    const float* bias1  = (const float*)d_in[6];
    const float* W2     = (const float*)d_in[7];
    const float* att_s2 = (const float*)d_in[8];
    const float* att_d2 = (const float*)d_in[9];
    const float* bias2  = (const float*)d_in[10];
    const float* Wih    = (const float*)d_in[11];
    const float* Whh    = (const float*)d_in[12];
    const float* bih    = (const float*)d_in[13];
    const float* bhh    = (const float*)d_in[14];
    const float* Wf1    = (const float*)d_in[15];
    const float* bf1    = (const float*)d_in[16];
    const float* Wf2    = (const float*)d_in[17];
    const float* bf2    = (const float*)d_in[18];
    float* out = (float*)d_out;

    const int N  = in_sizes[0] / IN_F;   // 50000
    const int E  = in_sizes[1] / 2;      // 800000
    const int ET = E + N;
    const int* srcs = eidx;
    const int* dsts = eidx + E;

    // workspace layout
    float* fws = (float*)d_ws;
    size_t o = 0;
    float* h1  = fws + o; o += (size_t)N * 256;
    float* g1  = fws + o; o += (size_t)N * 256;
    float* tt  = fws + o; o += (size_t)N * 32;   // dedicated (r21 race fix)
    float* as1 = fws + o; o += (size_t)N * 4;
    float* ad1 = fws + o; o += (size_t)N * 4;
    int* cnt    = (int*)(fws + o);
    int* rowp   = cnt + N;
    int* cursor = rowp + N + 1;
    int* eid    = cursor + N;
    int* bsum   = eid + ET;
    uintptr_t wp_ = (uintptr_t)(bsum + 512);
    wp_ = (wp_ + 15) & ~(uintptr_t)15;
    uint32x4* wsp = (uint32x4*)wp_;
    unsigned short* w1h = (unsigned short*)(wsp + 1536);
    unsigned short* w1l = w1h + 32768;
    unsigned short* w2h = w1l + 32768;
    unsigned short* w2l = w2h + 16384;
    // layer-2 aliases (h1 region dead after the fused agg4||lstm kernel)
    float* h2 = h1;                      // N*64
    float* as2 = as1; float* ad2 = ad1;

    const int nTiles = (N + 255) / 256;
    dim3 blk(256);

    hipMemsetAsync(cnt, 0, (size_t)N * sizeof(int), stream);
    hipMemsetAsync(cursor, 0, (size_t)N * sizeof(int), stream);

    // ---- weight prepacks (tiny, once) ----
    prep_wsplit<<<1, 512, 0, stream>>>(Wih, Whh, bih, bhh, wsp);
    prep_wt<128><<<(32768 + 255) / 256, blk, 0, stream>>>(W1, w1h, w1l, 32768, 256);
    prep_wt<256><<<(16384 + 255) / 256, blk, 0, stream>>>(W2, w2h, w2l, 16384, 64);

    // ---- FUSED gemm1 || count_deg ----
    {
        const int nGemmRow = (N + 127) / 128;            // 391
        const int nCount   = (ET + 255) / 256;           // 3320
        gemm1_count<<<nGemmRow * 4 + nCount, blk, 0, stream>>>(
            x, w1h, w1l, h1, N, dsts, E, ET, cnt, nGemmRow);
    }

    // ---- CSR scans ----
    scan1<<<nTiles, blk, 0, stream>>>(cnt, rowp, bsum, N);
    scan2<<<1, blk, 0, stream>>>(bsum, nTiles);
    scan3<<<(N + 256) / 256, blk, 0, stream>>>(rowp, bsum, N, ET);

    // ---- FUSED att_scores1 || scatter_edges ----
    {
        const int nScore = (N * 4 + 255) / 256;          // 782
        const int nScat  = (ET + 255) / 256;             // 3320
        sc1_scatter<<<nScore + nScat, blk, 0, stream>>>(
            h1, att_s1, att_d1, as1, ad1, N * 4, dsts, E, ET, rowp, cursor, eid, nScore);
    }

    // ---- FUSED agg4 || lstm ----
    {
        const int nLstm = (N + 31) / 32;                 // 1563
        const int nAgg  = (N + 3) / 4;                   // 12500
        agg4_lstm<<<nLstm + nAgg, blk, 0, stream>>>(srcs, E, rowp, eid, as1, ad1,
                                                    h1, bias1, g1, seq, wsp, tt, N, nLstm);
    }

    // ---- GAT layer 2 GEMM + scores ----
    gemm_mfma<256, 64><<<dim3((N + 127) / 128, 1), blk, 0, stream>>>(g1, w2h, w2l, h2, N);
    att_scores<<<(N + 255) / 256, blk, 0, stream>>>(h2, att_s2, att_d2, as2, ad2, N, 0);

    // ---- FUSED agg1 + MLP -> writes out directly ----
    agg1_mlp<<<(N + 3) / 4, blk, 0, stream>>>(srcs, E, rowp, eid, as2, ad2, h2, bias2,
                                              tt, Wf1, bf1, Wf2, bf2, out, N);
}

// Round 16
// 659.546 us; speedup vs baseline: 1.1178x; 1.0560x over previous
//
#include <hip/hip_runtime.h>
#include <math.h>

#define HEADS1 4
#define HID 64
#define LSTM_H 32
#define IN_F 128
#define T_STEPS 50
#define NEG_SLOPE 0.2f
#define EPS_A 1e-16f

typedef __attribute__((ext_vector_type(8))) short short8;
typedef __attribute__((ext_vector_type(4))) float floatx4;
typedef __attribute__((ext_vector_type(4))) unsigned uint32x4;

// ---------- helpers ----------
__device__ __forceinline__ float frcp(float x) {
    float r;
    asm("v_rcp_f32 %0, %1" : "=v"(r) : "v"(x));
    return r;
}
__device__ __forceinline__ float sigf(float x) { return frcp(1.0f + __expf(-x)); }
__device__ __forceinline__ float tanhfast(float x) {
    float e = __expf(2.0f * x);
    return 1.0f - 2.0f * frcp(e + 1.0f);
}
__device__ __forceinline__ unsigned short f2bf(float f) {
    unsigned u = __float_as_uint(f);
    unsigned r = (u + 0x7FFFu + ((u >> 16) & 1u)) >> 16;
    return (unsigned short)r;
}
__device__ __forceinline__ float bf2f(unsigned short s) {
    return __uint_as_float(((unsigned)s) << 16);
}
__device__ __forceinline__ unsigned cvt_pk_bf16(float a, float b) {
    unsigned r;
    asm("v_cvt_pk_bf16_f32 %0, %1, %2" : "=v"(r) : "v"(a), "v"(b));
    return r;
}
__device__ __forceinline__ float lo16f(unsigned p) { return __uint_as_float(p << 16); }
__device__ __forceinline__ float hi16f(unsigned p) { return __uint_as_float(p & 0xffff0000u); }
__device__ __forceinline__ short8 bc8(uint32x4 v) { return __builtin_bit_cast(short8, v); }

// ---------- weight transpose+split prepack for MFMA GEMM ----------
template <int KK>
__global__ void prep_wt(const float* __restrict__ W, unsigned short* __restrict__ th,
                        unsigned short* __restrict__ tl, int total, int NC) {
    int i = blockIdx.x * 256 + threadIdx.x;
    if (i >= total) return;
    int n = i / KK, k = i - n * KK;
    float v = W[k * NC + n];
    unsigned short h = f2bf(v);
    th[i] = h;
    tl[i] = f2bf(v - bf2f(h));
}

// ---------- MFMA GEMM: C[M,NC] = A[M,K] @ B[K,NC], split-bf16 3-product ----
template <int K, int NC>
__global__ __launch_bounds__(256)
void gemm_mfma(const float* __restrict__ A, const unsigned short* __restrict__ Bth,
               const unsigned short* __restrict__ Btl, float* __restrict__ C, int M) {
    __shared__ float sA[128][44];
    __shared__ unsigned short sBh[64][40];
    __shared__ unsigned short sBl[64][40];
    const int tid = threadIdx.x;
    const int wave = tid >> 6, lane = tid & 63;
    const int wr = wave >> 1, wc = wave & 1;
    const int row0 = blockIdx.x * 128;
    const int col0 = blockIdx.y * 64;
    const int l15 = lane & 15, l4 = lane >> 4;

    floatx4 acc[4][2];
#pragma unroll
    for (int rb = 0; rb < 4; rb++)
#pragma unroll
        for (int cb = 0; cb < 2; cb++) acc[rb][cb] = (floatx4){0.f, 0.f, 0.f, 0.f};

    for (int k0 = 0; k0 < K; k0 += 32) {
        __syncthreads();
#pragma unroll
        for (int q = 0; q < 4; q++) {
            int idx = q * 256 + tid;
            int row = idx >> 3, seg = idx & 7;
            int gr = row0 + row;
            float4 v = (gr < M) ? *(const float4*)&A[(size_t)gr * K + k0 + seg * 4]
                                : make_float4(0.f, 0.f, 0.f, 0.f);
            *(float4*)&sA[row][seg * 4] = v;
        }
        {
            int col = tid >> 2, seg = tid & 3;
            size_t gb = (size_t)(col0 + col) * K + k0 + seg * 8;
            *(short8*)&sBh[col][seg * 8] = *(const short8*)&Bth[gb];
            *(short8*)&sBl[col][seg * 8] = *(const short8*)&Btl[gb];
        }
        __syncthreads();

        short8 bh0 = *(const short8*)&sBh[wc * 32 + 0 + l15][l4 * 8];
        short8 bl0 = *(const short8*)&sBl[wc * 32 + 0 + l15][l4 * 8];
        short8 bh1 = *(const short8*)&sBh[wc * 32 + 16 + l15][l4 * 8];
        short8 bl1 = *(const short8*)&sBl[wc * 32 + 16 + l15][l4 * 8];

#pragma unroll
        for (int rb = 0; rb < 4; rb++) {
            int row = wr * 64 + rb * 16 + l15;
            floatx4 a0 = *(const floatx4*)&sA[row][l4 * 8 + 0];
            floatx4 a1 = *(const floatx4*)&sA[row][l4 * 8 + 4];
            unsigned p0 = cvt_pk_bf16(a0[0], a0[1]);
            unsigned p1 = cvt_pk_bf16(a0[2], a0[3]);
            unsigned p2 = cvt_pk_bf16(a1[0], a1[1]);
            unsigned p3 = cvt_pk_bf16(a1[2], a1[3]);
            uint32x4 hp = {p0, p1, p2, p3};
            short8 Ah = bc8(hp);
            unsigned q0 = cvt_pk_bf16(a0[0] - lo16f(p0), a0[1] - hi16f(p0));
            unsigned q1 = cvt_pk_bf16(a0[2] - lo16f(p1), a0[3] - hi16f(p1));
            unsigned q2 = cvt_pk_bf16(a1[0] - lo16f(p2), a1[1] - hi16f(p2));
            unsigned q3 = cvt_pk_bf16(a1[2] - lo16f(p3), a1[3] - hi16f(p3));
            uint32x4 lp = {q0, q1, q2, q3};
            short8 Al = bc8(lp);

            acc[rb][0] = __builtin_amdgcn_mfma_f32_16x16x32_bf16(Ah, bh0, acc[rb][0], 0, 0, 0);
            acc[rb][0] = __builtin_amdgcn_mfma_f32_16x16x32_bf16(Ah, bl0, acc[rb][0], 0, 0, 0);
            acc[rb][0] = __builtin_amdgcn_mfma_f32_16x16x32_bf16(Al, bh0, acc[rb][0], 0, 0, 0);
            acc[rb][1] = __builtin_amdgcn_mfma_f32_16x16x32_bf16(Ah, bh1, acc[rb][1], 0, 0, 0);
            acc[rb][1] = __builtin_amdgcn_mfma_f32_16x16x32_bf16(Ah, bl1, acc[rb][1], 0, 0, 0);
            acc[rb][1] = __builtin_amdgcn_mfma_f32_16x16x32_bf16(Al, bh1, acc[rb][1], 0, 0, 0);
        }
    }

#pragma unroll
    for (int rb = 0; rb < 4; rb++)
#pragma unroll
        for (int cb = 0; cb < 2; cb++)
#pragma unroll
            for (int q = 0; q < 4; q++) {
                int row = row0 + wr * 64 + rb * 16 + l4 * 4 + q;
                int col = col0 + wc * 32 + cb * 16 + l15;
                if (row < M) C[(size_t)row * NC + col] = acc[rb][cb][q];
            }
}

// ---------- FUSED: gemm1 || count_deg (independent workloads) ----------
__global__ __launch_bounds__(256)
void gemm1_count(const float* __restrict__ A, const unsigned short* __restrict__ Bth,
                 const unsigned short* __restrict__ Btl, float* __restrict__ C, int M,
                 const int* __restrict__ dsts, int E, int ET, int* __restrict__ cnt,
                 int nGemmRow) {
    __shared__ float sA[128][44];
    __shared__ unsigned short sBh[64][40];
    __shared__ unsigned short sBl[64][40];
    const int bid = blockIdx.x;
    const int nGemm = nGemmRow * 4;

    if (bid >= nGemm) {
        int e = (bid - nGemm) * 256 + threadIdx.x;
        if (e < ET) {
            int d = (e < E) ? dsts[e] : (e - E);
            atomicAdd(&cnt[d], 1);
        }
        return;
    }

    constexpr int K = 128;
    const int tid = threadIdx.x;
    const int wave = tid >> 6, lane = tid & 63;
    const int wr = wave >> 1, wc = wave & 1;
    const int row0 = (bid / 4) * 128;
    const int col0 = (bid & 3) * 64;
    const int l15 = lane & 15, l4 = lane >> 4;

    floatx4 acc[4][2];
#pragma unroll
    for (int rb = 0; rb < 4; rb++)
#pragma unroll
        for (int cb = 0; cb < 2; cb++) acc[rb][cb] = (floatx4){0.f, 0.f, 0.f, 0.f};

    for (int k0 = 0; k0 < K; k0 += 32) {
        __syncthreads();
#pragma unroll
        for (int q = 0; q < 4; q++) {
            int idx = q * 256 + tid;
            int row = idx >> 3, seg = idx & 7;
            int gr = row0 + row;
            float4 v = (gr < M) ? *(const float4*)&A[(size_t)gr * K + k0 + seg * 4]
                                : make_float4(0.f, 0.f, 0.f, 0.f);
            *(float4*)&sA[row][seg * 4] = v;
        }
        {
            int col = tid >> 2, seg = tid & 3;
            size_t gb = (size_t)(col0 + col) * K + k0 + seg * 8;
            *(short8*)&sBh[col][seg * 8] = *(const short8*)&Bth[gb];
            *(short8*)&sBl[col][seg * 8] = *(const short8*)&Btl[gb];
        }
        __syncthreads();

        short8 bh0 = *(const short8*)&sBh[wc * 32 + 0 + l15][l4 * 8];
        short8 bl0 = *(const short8*)&sBl[wc * 32 + 0 + l15][l4 * 8];
        short8 bh1 = *(const short8*)&sBh[wc * 32 + 16 + l15][l4 * 8];
        short8 bl1 = *(const short8*)&sBl[wc * 32 + 16 + l15][l4 * 8];

#pragma unroll
        for (int rb = 0; rb < 4; rb++) {
            int row = wr * 64 + rb * 16 + l15;
            floatx4 a0 = *(const floatx4*)&sA[row][l4 * 8 + 0];
            floatx4 a1 = *(const floatx4*)&sA[row][l4 * 8 + 4];
            unsigned p0 = cvt_pk_bf16(a0[0], a0[1]);
            unsigned p1 = cvt_pk_bf16(a0[2], a0[3]);
            unsigned p2 = cvt_pk_bf16(a1[0], a1[1]);
            unsigned p3 = cvt_pk_bf16(a1[2], a1[3]);
            uint32x4 hp = {p0, p1, p2, p3};
            short8 Ah = bc8(hp);
            unsigned q0 = cvt_pk_bf16(a0[0] - lo16f(p0), a0[1] - hi16f(p0));
            unsigned q1 = cvt_pk_bf16(a0[2] - lo16f(p1), a0[3] - hi16f(p1));
            unsigned q2 = cvt_pk_bf16(a1[0] - lo16f(p2), a1[1] - hi16f(p2));
            unsigned q3 = cvt_pk_bf16(a1[2] - lo16f(p3), a1[3] - hi16f(p3));
            uint32x4 lp = {q0, q1, q2, q3};
            short8 Al = bc8(lp);

            acc[rb][0] = __builtin_amdgcn_mfma_f32_16x16x32_bf16(Ah, bh0, acc[rb][0], 0, 0, 0);
            acc[rb][0] = __builtin_amdgcn_mfma_f32_16x16x32_bf16(Ah, bl0, acc[rb][0], 0, 0, 0);
            acc[rb][0] = __builtin_amdgcn_mfma_f32_16x16x32_bf16(Al, bh0, acc[rb][0], 0, 0, 0);
            acc[rb][1] = __builtin_amdgcn_mfma_f32_16x16x32_bf16(Ah, bh1, acc[rb][1], 0, 0, 0);
            acc[rb][1] = __builtin_amdgcn_mfma_f32_16x16x32_bf16(Ah, bl1, acc[rb][1], 0, 0, 0);
            acc[rb][1] = __builtin_amdgcn_mfma_f32_16x16x32_bf16(Al, bh1, acc[rb][1], 0, 0, 0);
        }
    }

#pragma unroll
    for (int rb = 0; rb < 4; rb++)
#pragma unroll
        for (int cb = 0; cb < 2; cb++)
#pragma unroll
            for (int q = 0; q < 4; q++) {
                int row = row0 + wr * 64 + rb * 16 + l4 * 4 + q;
                int col = col0 + wc * 32 + cb * 16 + l15;
                if (row < M) C[(size_t)row * 256 + col] = acc[rb][cb][q];
            }
}

// ---------- FUSED: att_scores1 || scatter_edges ----------
// r24: scatter now stores the SRC NODE directly in eid (self-loop -> node id),
// removing the srcs[e] random pointer-chase level from both gather kernels.
__global__ void sc1_scatter(const float* __restrict__ h, const float* __restrict__ att_s,
                            const float* __restrict__ att_d, float* __restrict__ as_,
                            float* __restrict__ ad_, int NH,
                            const int* __restrict__ srcs, const int* __restrict__ dsts,
                            int E, int ET,
                            const int* __restrict__ rowp, int* __restrict__ cursor,
                            int* __restrict__ eid, int nScore) {
    const int bid = blockIdx.x;
    if (bid >= nScore) {
        int e = (bid - nScore) * 256 + threadIdx.x;
        if (e < ET) {
            int d = (e < E) ? dsts[e] : (e - E);
            int sv = (e < E) ? srcs[e] : (e - E);
            int pos = atomicAdd(&cursor[d], 1);
            eid[rowp[d] + pos] = sv;
        }
        return;
    }
    int i = bid * 256 + threadIdx.x;
    if (i >= NH) return;
    int hh = i & 3;
    const float* row = h + (size_t)i * HID;
    float s = 0.0f, d = 0.0f;
#pragma unroll 8
    for (int c = 0; c < HID; c++) {
        float v = row[c];
        s += v * att_s[hh * HID + c];
        d += v * att_d[hh * HID + c];
    }
    as_[i] = s;
    ad_[i] = d;
}

// ---------- attention scores (layer 2, standalone) ----------
__global__ void att_scores(const float* __restrict__ h, const float* __restrict__ att_s,
                           const float* __restrict__ att_d, float* __restrict__ as_,
                           float* __restrict__ ad_, int NH, int Hmask) {
    int i = blockIdx.x * blockDim.x + threadIdx.x;
    if (i >= NH) return;
    int hh = i & Hmask;
    const float* row = h + (size_t)i * HID;
    float s = 0.0f, d = 0.0f;
#pragma unroll 8
    for (int c = 0; c < HID; c++) {
        float v = row[c];
        s += v * att_s[hh * HID + c];
        d += v * att_d[hh * HID + c];
    }
    as_[i] = s;
    ad_[i] = d;
}

// ---------- CSR scans ----------
__global__ void scan1(const int* __restrict__ cnt, int* __restrict__ rowp,
                      int* __restrict__ bsum, int N) {
    __shared__ int tmp[256];
    int i = blockIdx.x * 256 + threadIdx.x;
    int v = (i < N) ? cnt[i] : 0;
    tmp[threadIdx.x] = v;
    __syncthreads();
    for (int off = 1; off < 256; off <<= 1) {
        int t = (threadIdx.x >= (unsigned)off) ? tmp[threadIdx.x - off] : 0;
        __syncthreads();
        tmp[threadIdx.x] += t;
        __syncthreads();
    }
    if (i < N) rowp[i] = tmp[threadIdx.x] - v;
    if (threadIdx.x == 255) bsum[blockIdx.x] = tmp[255];
}

__global__ void scan2(int* __restrict__ bsum, int nb) {
    __shared__ int tmp[256];
    int v = (threadIdx.x < (unsigned)nb) ? bsum[threadIdx.x] : 0;
    tmp[threadIdx.x] = v;
    __syncthreads();
    for (int off = 1; off < 256; off <<= 1) {
        int t = (threadIdx.x >= (unsigned)off) ? tmp[threadIdx.x - off] : 0;
        __syncthreads();
        tmp[threadIdx.x] += t;
        __syncthreads();
    }
    if (threadIdx.x < (unsigned)nb) bsum[threadIdx.x] = tmp[threadIdx.x] - v;
}

__global__ void scan3(int* __restrict__ rowp, const int* __restrict__ bsum, int N, int ET) {
    int i = blockIdx.x * 256 + threadIdx.x;
    if (i < N) rowp[i] += bsum[blockIdx.x];
    if (i == 0) rowp[N] = ET;
}

// ---------- LSTM weight prepack (runs once, 1 block) ----------
__global__ void prep_wsplit(const float* __restrict__ Wih, const float* __restrict__ Whh,
                            const float* __restrict__ bih, const float* __restrict__ bhh,
                            uint32x4* __restrict__ wsp) {
    const int tid = threadIdx.x;          // 0..511
    const int kk = tid >> 7, sub = (tid >> 6) & 1, lane = tid & 63;
    const int grp = lane >> 4, col = lane & 15;
    const int krow = grp * 8;
    const int n = (sub + kk * 2) * 16 + col;
    float w[8];
    *(float4*)&w[0] = *(const float4*)&Whh[n * 32 + krow + 0];
    *(float4*)&w[4] = *(const float4*)&Whh[n * 32 + krow + 4];
    unsigned hi[8], lo[8];
#pragma unroll
    for (int j = 0; j < 8; j++) {
        unsigned short hs = f2bf(w[j]);
        hi[j] = hs;
        lo[j] = f2bf(w[j] - bf2f(hs));
    }
    uint32x4 BH = {hi[0] | (hi[1] << 16), hi[2] | (hi[3] << 16),
                   hi[4] | (hi[5] << 16), hi[6] | (hi[7] << 16)};
    uint32x4 BL = {lo[0] | (lo[1] << 16), lo[2] | (lo[3] << 16),
                   lo[4] | (lo[5] << 16), lo[6] | (lo[7] << 16)};
    float wi0 = Wih[n * 3 + 0], wi1 = Wih[n * 3 + 1], wi2 = Wih[n * 3 + 2];
    float bb = bih[n] + bhh[n];
    unsigned h0 = f2bf(wi0), h1 = f2bf(wi1), h2 = f2bf(wi2), hb = f2bf(bb);
    uint32x4 B2 = {0u, 0u, 0u, 0u};
    if (grp == 0) {
        unsigned bl_ = f2bf(bb - bf2f((unsigned short)hb));
        B2[0] = h0 | (h1 << 16); B2[1] = h2 | (hb << 16);
        B2[2] = h0 | (h1 << 16); B2[3] = h2 | (bl_ << 16);
    } else if (grp == 1) {
        unsigned l0 = f2bf(wi0 - bf2f((unsigned short)h0));
        unsigned l1 = f2bf(wi1 - bf2f((unsigned short)h1));
        unsigned l2 = f2bf(wi2 - bf2f((unsigned short)h2));
        B2[0] = l0 | (l1 << 16); B2[1] = l2;
    }
    wsp[((kk * 3 + 0) * 2 + sub) * 64 + lane] = B2;
    wsp[((kk * 3 + 1) * 2 + sub) * 64 + lane] = BH;
    wsp[((kk * 3 + 2) * 2 + sub) * 64 + lane] = BL;
}

// ---------- FUSED: gat_agg4 || lstm (round-24: lstm-FIRST packing) ----------
// r23 post-mortem: fused dur 320 ~= lstm(180)+agg4(140) = SUM -- overlap
// failed because the 1:9 interleave dispatched the LAST lstm blocks ~150us in
// (after 12K quick agg4 blocks), and they then ran their 180us nearly solo.
// Fix: lstm blocks are blockIdx 0..nLstm-1 so ALL long-pole blocks start at
// t=0 (1563 blocks = 6.1/CU = 24 waves/CU), agg4's 12500 short blocks churn
// in the remaining slots. Also: eid now holds src directly (one less random
// load per edge) and gather unroll 8.
__global__ __launch_bounds__(256)
void agg4_lstm(const int* __restrict__ rowp, const int* __restrict__ eid,
               const float* __restrict__ as_, const float* __restrict__ ad_,
               const float* __restrict__ hfeat, const float* __restrict__ bias,
               float* __restrict__ g,
               const float* __restrict__ seq, const uint32x4* __restrict__ wsp,
               float* __restrict__ t_out, int N, int nLstm) {
    __shared__ float smem[2304];

    const int bid = blockIdx.x;

    if (bid < nLstm) {
        // ================= LSTM body (pair-split, prepacked frags) =====
        float (*s_h)[2][16][36] = (float(*)[2][16][36])smem;
        const int tid  = threadIdx.x;
        const int wave = tid >> 6, lane = tid & 63;
        const int pair = wave >> 1, sub = wave & 1;
        const int grp  = lane >> 4, col = lane & 15;
        const int node0 = bid * 32 + pair * 16;

#define LF(KK, W) wsp[(((KK) * 3 + (W)) * 2 + sub) * 64 + lane]
        uint32x4 B2_0 = LF(0, 0), BH_0 = LF(0, 1), BL_0 = LF(0, 2);
        uint32x4 B2_1 = LF(1, 0), BH_1 = LF(1, 1), BL_1 = LF(1, 2);
        uint32x4 B2_2 = LF(2, 0), BH_2 = LF(2, 1), BL_2 = LF(2, 2);
        uint32x4 B2_3 = LF(3, 0), BH_3 = LF(3, 1), BL_3 = LF(3, 2);
#undef LF
        asm volatile("" : "+v"(B2_0), "+v"(BH_0), "+v"(BL_0),
                          "+v"(B2_1), "+v"(BH_1), "+v"(BL_1),
                          "+v"(B2_2), "+v"(BH_2), "+v"(BL_2),
                          "+v"(B2_3), "+v"(BH_3), "+v"(BL_3));

        for (int i = tid; i < 2 * 2 * 16 * 36; i += 256) smem[i] = 0.0f;
        __syncthreads();

        float cst0 = 0.f, cst1 = 0.f, cst2 = 0.f, cst3 = 0.f;
        float hn0 = 0.f, hn1 = 0.f, hn2 = 0.f, hn3 = 0.f;
        const floatx4 zac = {0.f, 0.f, 0.f, 0.f};

        const int nodeX = node0 + col;
        const bool vx = (nodeX < N) && (grp < 2);
        const bool g0 = (grp == 0);
        const float* xp = seq + (size_t)nodeX * (T_STEPS * 3);

        float xv0 = vx ? xp[0] : 0.0f;
        float xv1 = vx ? xp[1] : 0.0f;
        float xv2 = vx ? xp[2] : 0.0f;

#pragma unroll 1
        for (int t = 0; t < T_STEPS; t++) {
            unsigned w0 = cvt_pk_bf16(xv0, xv1);
            unsigned w1 = cvt_pk_bf16(xv2, g0 ? 1.0f : 0.0f);
            float e0 = xv0 - lo16f(w0);
            float e1 = xv1 - hi16f(w0);
            float e2 = xv2 - lo16f(w1);
            unsigned w2 = g0 ? cvt_pk_bf16(e0, e1) : 0u;
            unsigned w3 = g0 ? cvt_pk_bf16(e2, 1.0f) : 0u;
            uint32x4 a2p = {w0, w1, w2, w3};
            short8 A2 = bc8(a2p);

            const float* hr = &s_h[pair][(t + 1) & 1][col][grp * 8];
            floatx4 h0 = *(const floatx4*)&hr[0];
            floatx4 h1 = *(const floatx4*)&hr[4];
            unsigned p0 = cvt_pk_bf16(h0[0], h0[1]);
            unsigned p1 = cvt_pk_bf16(h0[2], h0[3]);
            unsigned p2 = cvt_pk_bf16(h1[0], h1[1]);
            unsigned p3 = cvt_pk_bf16(h1[2], h1[3]);
            uint32x4 hip = {p0, p1, p2, p3};
            short8 Ahi = bc8(hip);
            unsigned q0 = cvt_pk_bf16(h0[0] - lo16f(p0), h0[1] - hi16f(p0));
            unsigned q1 = cvt_pk_bf16(h0[2] - lo16f(p1), h0[3] - hi16f(p1));
            unsigned q2 = cvt_pk_bf16(h1[0] - lo16f(p2), h1[1] - hi16f(p2));
            unsigned q3 = cvt_pk_bf16(h1[2] - lo16f(p3), h1[3] - hi16f(p3));
            uint32x4 lop = {q0, q1, q2, q3};
            short8 Alo = bc8(lop);

            {
                int tn = (t + 1 < T_STEPS) ? (t + 1) : t;
                xv0 = vx ? xp[tn * 3 + 0] : 0.0f;
                xv1 = vx ? xp[tn * 3 + 1] : 0.0f;
                xv2 = vx ? xp[tn * 3 + 2] : 0.0f;
            }

            floatx4 d0 = __builtin_amdgcn_mfma_f32_16x16x32_bf16(A2, bc8(B2_0), zac, 0, 0, 0);
            d0 = __builtin_amdgcn_mfma_f32_16x16x32_bf16(Alo, bc8(BH_0), d0, 0, 0, 0);
            d0 = __builtin_amdgcn_mfma_f32_16x16x32_bf16(Ahi, bc8(BL_0), d0, 0, 0, 0);
            d0 = __builtin_amdgcn_mfma_f32_16x16x32_bf16(Ahi, bc8(BH_0), d0, 0, 0, 0);
            floatx4 d1 = __builtin_amdgcn_mfma_f32_16x16x32_bf16(A2, bc8(B2_1), zac, 0, 0, 0);
            d1 = __builtin_amdgcn_mfma_f32_16x16x32_bf16(Alo, bc8(BH_1), d1, 0, 0, 0);
            d1 = __builtin_amdgcn_mfma_f32_16x16x32_bf16(Ahi, bc8(BL_1), d1, 0, 0, 0);
            d1 = __builtin_amdgcn_mfma_f32_16x16x32_bf16(Ahi, bc8(BH_1), d1, 0, 0, 0);
            floatx4 d2 = __builtin_amdgcn_mfma_f32_16x16x32_bf16(A2, bc8(B2_2), zac, 0, 0, 0);
            d2 = __builtin_amdgcn_mfma_f32_16x16x32_bf16(Alo, bc8(BH_2), d2, 0, 0, 0);
            d2 = __builtin_amdgcn_mfma_f32_16x16x32_bf16(Ahi, bc8(BL_2), d2, 0, 0, 0);
            d2 = __builtin_amdgcn_mfma_f32_16x16x32_bf16(Ahi, bc8(BH_2), d2, 0, 0, 0);
            floatx4 d3 = __builtin_amdgcn_mfma_f32_16x16x32_bf16(A2, bc8(B2_3), zac, 0, 0, 0);
            d3 = __builtin_amdgcn_mfma_f32_16x16x32_bf16(Alo, bc8(BH_3), d3, 0, 0, 0);
            d3 = __builtin_amdgcn_mfma_f32_16x16x32_bf16(Ahi, bc8(BL_3), d3, 0, 0, 0);
            d3 = __builtin_amdgcn_mfma_f32_16x16x32_bf16(Ahi, bc8(BH_3), d3, 0, 0, 0);

            {
                float ig, fg, gv, og;
                ig = sigf(d0[0]); fg = sigf(d1[0]); gv = tanhfast(d2[0]); og = sigf(d3[0]);
                cst0 = fg * cst0 + ig * gv; hn0 = og * tanhfast(cst0);
                ig = sigf(d0[1]); fg = sigf(d1[1]); gv = tanhfast(d2[1]); og = sigf(d3[1]);
                cst1 = fg * cst1 + ig * gv; hn1 = og * tanhfast(cst1);
                ig = sigf(d0[2]); fg = sigf(d1[2]); gv = tanhfast(d2[2]); og = sigf(d3[2]);
                cst2 = fg * cst2 + ig * gv; hn2 = og * tanhfast(cst2);
                ig = sigf(d0[3]); fg = sigf(d1[3]); gv = tanhfast(d2[3]); og = sigf(d3[3]);
                cst3 = fg * cst3 + ig * gv; hn3 = og * tanhfast(cst3);
            }

            float* hw = &s_h[pair][t & 1][4 * grp][sub * 16 + col];
            hw[0 * 36] = hn0; hw[1 * 36] = hn1; hw[2 * 36] = hn2; hw[3 * 36] = hn3;
            __syncthreads();
        }

        {
            int node = node0 + 4 * grp;
            const int c = sub * 16 + col;
            if (node + 0 < N) t_out[(size_t)(node + 0) * LSTM_H + c] = hn0;
            if (node + 1 < N) t_out[(size_t)(node + 1) * LSTM_H + c] = hn1;
            if (node + 2 < N) t_out[(size_t)(node + 2) * LSTM_H + c] = hn2;
            if (node + 3 < N) t_out[(size_t)(node + 3) * LSTM_H + c] = hn3;
        }
        return;
    }

    // ================= agg4 body (eid holds src directly) ==================
    {
        float (*s_alpha)[64][4] = (float(*)[64][4])smem;
        const int aid = bid - nLstm;
        const int wave = threadIdx.x >> 6;
        const int lane = threadIdx.x & 63;
        const int head = lane >> 4;
        const int dst = aid * 4 + wave;
        if (dst >= N) return;
        const int start = rowp[dst], end = rowp[dst + 1];
        const float4 adv = ((const float4*)ad_)[dst];
        const float4* h4 = (const float4*)hfeat;

        float4 dsum = make_float4(0.f, 0.f, 0.f, 0.f);
        float4 acc  = make_float4(0.f, 0.f, 0.f, 0.f);

        for (int i0 = start; i0 < end; i0 += 64) {
            int cnt = min(64, end - i0);
            int i = i0 + lane;
            int s = 0;
            if (i < end) {
                s = eid[i];
                float4 a = ((const float4*)as_)[s];
                float tx, ex;
                tx = a.x + adv.x; tx = (tx > 0.f) ? tx : NEG_SLOPE * tx; ex = __expf(tx);
                dsum.x += ex; s_alpha[wave][lane][0] = ex;
                tx = a.y + adv.y; tx = (tx > 0.f) ? tx : NEG_SLOPE * tx; ex = __expf(tx);
                dsum.y += ex; s_alpha[wave][lane][1] = ex;
                tx = a.z + adv.z; tx = (tx > 0.f) ? tx : NEG_SLOPE * tx; ex = __expf(tx);
                dsum.z += ex; s_alpha[wave][lane][2] = ex;
                tx = a.w + adv.w; tx = (tx > 0.f) ? tx : NEG_SLOPE * tx; ex = __expf(tx);
                dsum.w += ex; s_alpha[wave][lane][3] = ex;
            }
            __builtin_amdgcn_wave_barrier();
#pragma unroll 8
            for (int k = 0; k < cnt; k++) {
                float a_k = s_alpha[wave][k][head];
                int   s_k = __shfl(s, k);
                float4 hv = h4[(size_t)s_k * 64 + lane];
                acc.x += a_k * hv.x; acc.y += a_k * hv.y;
                acc.z += a_k * hv.z; acc.w += a_k * hv.w;
            }
            __builtin_amdgcn_wave_barrier();
        }
#pragma unroll
        for (int mk = 32; mk >= 1; mk >>= 1) {
            dsum.x += __shfl_xor(dsum.x, mk);
            dsum.y += __shfl_xor(dsum.y, mk);
            dsum.z += __shfl_xor(dsum.z, mk);
            dsum.w += __shfl_xor(dsum.w, mk);
        }
        float den = (head == 0) ? dsum.x : (head == 1) ? dsum.y : (head == 2) ? dsum.z : dsum.w;
        float inv = 1.0f / (den + EPS_A);
        float4 b4 = ((const float4*)bias)[lane];
        float4 r;
        r.x = acc.x * inv + b4.x; r.x = (r.x > 0.f) ? r.x : __expf(r.x) - 1.f;
        r.y = acc.y * inv + b4.y; r.y = (r.y > 0.f) ? r.y : __expf(r.y) - 1.f;
        r.z = acc.z * inv + b4.z; r.z = (r.z > 0.f) ? r.z : __expf(r.z) - 1.f;
        r.w = acc.w * inv + b4.w; r.w = (r.w > 0.f) ? r.w : __expf(r.w) - 1.f;
        ((float4*)g)[(size_t)dst * 64 + lane] = r;
    }
}

// ---------- FUSED: gat_agg1 + fusion MLP (eid holds src directly) ----------
__global__ __launch_bounds__(256)
void agg1_mlp(const int* __restrict__ rowp, const int* __restrict__ eid,
              const float* __restrict__ as_, const float* __restrict__ ad_,
              const float* __restrict__ hfeat, const float* __restrict__ bias,
              const float* __restrict__ tt,
              const float* __restrict__ Wf1, const float* __restrict__ bf1,
              const float* __restrict__ Wf2, const float* __restrict__ bf2,
              float* __restrict__ out, int N) {
    __shared__ float s_alpha[4][64];
    __shared__ float sW[96 * 64];
    __shared__ float sb1[64];
    __shared__ float sW2[128];
    for (int i = threadIdx.x; i < 96 * 64; i += 256) sW[i] = Wf1[i];
    if (threadIdx.x < 64) sb1[threadIdx.x] = bf1[threadIdx.x];
    if (threadIdx.x < 128) sW2[threadIdx.x] = Wf2[threadIdx.x];
    __syncthreads();

    const int wave = threadIdx.x >> 6;
    const int lane = threadIdx.x & 63;
    const int dst = blockIdx.x * 4 + wave;
    if (dst >= N) return;
    const int start = rowp[dst], end = rowp[dst + 1];
    const float adv = ad_[dst];

    float dsum = 0.0f, acc = 0.0f;
    for (int i0 = start; i0 < end; i0 += 64) {
        int cnt = min(64, end - i0);
        int i = i0 + lane;
        int s = 0;
        if (i < end) {
            s = eid[i];
            float t = as_[s] + adv;
            t = (t > 0.f) ? t : NEG_SLOPE * t;
            float ex = __expf(t);
            dsum += ex;
            s_alpha[wave][lane] = ex;
        }
        __builtin_amdgcn_wave_barrier();
#pragma unroll 8
        for (int k = 0; k < cnt; k++) {
            float a_k = s_alpha[wave][k];
            int   s_k = __shfl(s, k);
            acc += a_k * hfeat[(size_t)s_k * 64 + lane];
        }
        __builtin_amdgcn_wave_barrier();
    }
#pragma unroll
    for (int mk = 32; mk >= 1; mk >>= 1) dsum += __shfl_xor(dsum, mk);
    const float gval = acc / (dsum + EPS_A) + bias[lane];

    // ---- MLP (same order as original fusion_kernel) ----
    float tval = (lane < 32) ? tt[(size_t)dst * 32 + lane] : 0.0f;
    float m = sb1[lane];
#pragma unroll 8
    for (int k = 0; k < 64; k++) m += __shfl(gval, k) * sW[k * 64 + lane];
#pragma unroll 8
    for (int k = 0; k < 32; k++) m += __shfl(tval, k) * sW[(64 + k) * 64 + lane];
    m = fmaxf(m, 0.0f);
    float o0 = m * sW2[lane * 2 + 0];
    float o1 = m * sW2[lane * 2 + 1];
#pragma unroll
    for (int mk = 32; mk >= 1; mk >>= 1) {
        o0 += __shfl_xor(o0, mk);
        o1 += __shfl_xor(o1, mk);
    }
    if (lane == 0) {
        out[(size_t)dst * 2 + 0] = o0 + bf2[0];
        out[(size_t)dst * 2 + 1] = o1 + bf2[1];
    }
}

extern "C" void kernel_launch(void* const* d_in, const int* in_sizes, int n_in,
                              void* d_out, int out_size, void* d_ws, size_t ws_size,
                              hipStream_t stream) {
    const float* x      = (const float*)d_in[0];
    const int*   eidx   = (const int*)d_in[1];
    const float* seq    = (const float*)d_in[2];
    const float* W1     = (const float*)d_in[3];
    const float* att_s1 = (const float*)d_in[4];
    const float* att_d1 = (const float*)d_in[5];
    const float* bias1  = (const float*)d_in[6];
    const float* W2     = (const float*)d_in[7];
    const float* att_s2 = (const float*)d_in[8];
    const float* att_d2 = (const float*)d_in[9];
    const float* bias2  = (const float*)d_in[10];
    const float* Wih    = (const float*)d_in[11];
    const float* Whh    = (const float*)d_in[12];
    const float* bih    = (const float*)d_in[13];
    const float* bhh    = (const float*)d_in[14];
    const float* Wf1    = (const float*)d_in[15];
    const float* bf1    = (const float*)d_in[16];
    const float* Wf2    = (const float*)d_in[17];
    const float* bf2    = (const float*)d_in[18];
    float* out = (float*)d_out;

    const int N  = in_sizes[0] / IN_F;   // 50000
    const int E  = in_sizes[1] / 2;      // 800000
    const int ET = E + N;
    const int* srcs = eidx;
    const int* dsts = eidx + E;

    // workspace layout
    float* fws = (float*)d_ws;
    size_t o = 0;
    float* h1  = fws + o; o += (size_t)N * 256;
    float* g1  = fws + o; o += (size_t)N * 256;
    float* tt  = fws + o; o += (size_t)N * 32;   // dedicated (r21 race fix)
    float* as1 = fws + o; o += (size_t)N * 4;
    float* ad1 = fws + o; o += (size_t)N * 4;
    int* cnt    = (int*)(fws + o);
    int* rowp   = cnt + N;
    int* cursor = rowp + N + 1;
    int* eid    = cursor + N;
    int* bsum   = eid + ET;
    uintptr_t wp_ = (uintptr_t)(bsum + 512);
    wp_ = (wp_ + 15) & ~(uintptr_t)15;
    uint32x4* wsp = (uint32x4*)wp_;
    unsigned short* w1h = (unsigned short*)(wsp + 1536);
    unsigned short* w1l = w1h + 32768;
    unsigned short* w2h = w1l + 32768;
    unsigned short* w2l = w2h + 16384;
    // layer-2 aliases (h1 region dead after the fused agg4||lstm kernel)
    float* h2 = h1;                      // N*64
    float* as2 = as1; float* ad2 = ad1;

    const int nTiles = (N + 255) / 256;
    dim3 blk(256);

    hipMemsetAsync(cnt, 0, (size_t)N * sizeof(int), stream);
    hipMemsetAsync(cursor, 0, (size_t)N * sizeof(int), stream);

    // ---- weight prepacks (tiny, once) ----
    prep_wsplit<<<1, 512, 0, stream>>>(Wih, Whh, bih, bhh, wsp);
    prep_wt<128><<<(32768 + 255) / 256, blk, 0, stream>>>(W1, w1h, w1l, 32768, 256);
    prep_wt<256><<<(16384 + 255) / 256, blk, 0, stream>>>(W2, w2h, w2l, 16384, 64);

    // ---- FUSED gemm1 || count_deg ----
    {
        const int nGemmRow = (N + 127) / 128;            // 391
        const int nCount   = (ET + 255) / 256;           // 3320
        gemm1_count<<<nGemmRow * 4 + nCount, blk, 0, stream>>>(
            x, w1h, w1l, h1, N, dsts, E, ET, cnt, nGemmRow);
    }

    // ---- CSR scans ----
    scan1<<<nTiles, blk, 0, stream>>>(cnt, rowp, bsum, N);
    scan2<<<1, blk, 0, stream>>>(bsum, nTiles);
    scan3<<<(N + 256) / 256, blk, 0, stream>>>(rowp, bsum, N, ET);

    // ---- FUSED att_scores1 || scatter_edges (eid <- src) ----
    {
        const int nScore = (N * 4 + 255) / 256;          // 782
        const int nScat  = (ET + 255) / 256;             // 3320
        sc1_scatter<<<nScore + nScat, blk, 0, stream>>>(
            h1, att_s1, att_d1, as1, ad1, N * 4, srcs, dsts, E, ET, rowp, cursor, eid, nScore);
    }

    // ---- FUSED agg4 || lstm (lstm blocks FIRST) ----
    {
        const int nLstm = (N + 31) / 32;                 // 1563
        const int nAgg  = (N + 3) / 4;                   // 12500
        agg4_lstm<<<nLstm + nAgg, blk, 0, stream>>>(rowp, eid, as1, ad1,
                                                    h1, bias1, g1, seq, wsp, tt, N, nLstm);
    }

    // ---- GAT layer 2 GEMM + scores ----
    gemm_mfma<256, 64><<<dim3((N + 127) / 128, 1), blk, 0, stream>>>(g1, w2h, w2l, h2, N);
    att_scores<<<(N + 255) / 256, blk, 0, stream>>>(h2, att_s2, att_d2, as2, ad2, N, 0);

    // ---- FUSED agg1 + MLP -> writes out directly ----
    agg1_mlp<<<(N + 3) / 4, blk, 0, stream>>>(rowp, eid, as2, ad2, h2, bias2,
                                              tt, Wf1, bf1, Wf2, bf2, out, N);
}